// Round 3
// baseline (1862.424 us; speedup 1.0000x reference)
//
#include <hip/hip_runtime.h>
#include <math.h>

#define D_ 512
#define K_ 8192
#define N_ 8192

#define BM 64
#define BN 128
#define DK 32
#define KSLICES 8
#define KSL (K_ / KSLICES)   // 1024

// ---- x2[n] = np.sum(x*x, axis=1) replicated: numpy pairwise f32 ----
// 512 = (128+128)+(128+128); each 128-block: 8 accumulators stride 8,
// combine ((r0+r1)+(r2+r3))+((r4+r5)+(r6+r7)); total (b0+b1)+(b2+b3).
__global__ void x2_kernel(const float* __restrict__ x, float* __restrict__ x2f) {
    int n = blockIdx.x * 256 + threadIdx.x;
    const float* row = &x[(size_t)n * D_];
    float b[4];
    #pragma unroll
    for (int blk = 0; blk < 4; ++blk) {
        const float* a = row + blk * 128;
        float r[8];
        #pragma unroll
        for (int j = 0; j < 8; ++j) { float v = a[j]; r[j] = __fmul_rn(v, v); }
        for (int i = 8; i < 128; i += 8) {
            #pragma unroll
            for (int j = 0; j < 8; ++j) {
                float v = a[i + j];
                r[j] = __fadd_rn(r[j], __fmul_rn(v, v));
            }
        }
        b[blk] = __fadd_rn(__fadd_rn(__fadd_rn(r[0], r[1]), __fadd_rn(r[2], r[3])),
                           __fadd_rn(__fadd_rn(r[4], r[5]), __fadd_rn(r[6], r[7])));
    }
    x2f[n] = __fadd_rn(__fadd_rn(b[0], b[1]), __fadd_rn(b[2], b[3]));
}

// ---- e2[k] = np.sum(e*e, axis=0) replicated: sequential f32 over d ----
__global__ void e2f_kernel(const float* __restrict__ e, float* __restrict__ e2f) {
    int k = blockIdx.x * 256 + threadIdx.x;
    float s = 0.0f;
    for (int d = 0; d < D_; ++d) {
        float v = e[(size_t)d * K_ + k];
        s = __fadd_rn(s, __fmul_rn(v, v));
    }
    e2f[k] = s;
}

// ---- fused distance-matmul (f64-exact dot) + f32-replicated score + argmin ----
__launch_bounds__(256, 2)
__global__ void argmin_kernel(const float* __restrict__ x, const float* __restrict__ e,
                              const float* __restrict__ x2f, const float* __restrict__ e2f,
                              float* __restrict__ pv, int* __restrict__ pi) {
    __shared__ float xs[DK][BM + 4];   // transposed x tile
    __shared__ float es[DK][BN + 4];
    __shared__ float redv[BM][16];
    __shared__ int   redi[BM][16];

    const int tid = threadIdx.x;
    const int tx = tid & 15, ty = tid >> 4;
    const int rowbase = blockIdx.y * BM;
    const int kslice  = blockIdx.x;
    const int ksbase  = kslice * KSL;

    float x2r[4];
    #pragma unroll
    for (int r = 0; r < 4; ++r) x2r[r] = x2f[rowbase + (ty << 2) + r];

    float bestv[4];
    int   besti[4];
    #pragma unroll
    for (int r = 0; r < 4; ++r) { bestv[r] = 3.0e38f; besti[r] = 0; }

    for (int kt = 0; kt < KSL / BN; ++kt) {
        const int kbase = ksbase + kt * BN;
        double acc[4][8];
        #pragma unroll
        for (int r = 0; r < 4; ++r)
            #pragma unroll
            for (int c = 0; c < 8; ++c)
                acc[r][c] = 0.0;

        for (int d0 = 0; d0 < D_; d0 += DK) {
            #pragma unroll
            for (int j = 0; j < 2; ++j) {
                int i = tid + j * 256;          // 0..511
                int r = i >> 3;                 // 0..63
                int dq = (i & 7) << 2;          // 0,4,..,28
                const float4 v = *(const float4*)(&x[(size_t)(rowbase + r) * D_ + d0 + dq]);
                xs[dq + 0][r] = v.x; xs[dq + 1][r] = v.y;
                xs[dq + 2][r] = v.z; xs[dq + 3][r] = v.w;
            }
            #pragma unroll
            for (int j = 0; j < 4; ++j) {
                int i = tid + j * 256;          // 0..1023
                int dd = i >> 5;                // 0..31
                int c4 = (i & 31) << 2;         // 0..124
                *(float4*)(&es[dd][c4]) = *(const float4*)(&e[(size_t)(d0 + dd) * K_ + kbase + c4]);
            }
            __syncthreads();
            #pragma unroll
            for (int dk = 0; dk < DK; ++dk) {
                const float4 xv = *(const float4*)(&xs[dk][ty << 2]);
                const float4 ea = *(const float4*)(&es[dk][tx << 3]);
                const float4 eb = *(const float4*)(&es[dk][(tx << 3) + 4]);
                const double xr[4] = {(double)xv.x, (double)xv.y, (double)xv.z, (double)xv.w};
                const double ec[8] = {(double)ea.x, (double)ea.y, (double)ea.z, (double)ea.w,
                                      (double)eb.x, (double)eb.y, (double)eb.z, (double)eb.w};
                #pragma unroll
                for (int r = 0; r < 4; ++r)
                    #pragma unroll
                    for (int c = 0; c < 8; ++c)
                        acc[r][c] = fma(xr[r], ec[c], acc[r][c]);
            }
            __syncthreads();
        }
        // replicated-f32 score: s = fl32( fl32(x2 + e2[k]) - 2*fl32(dot) )
        #pragma unroll
        for (int c = 0; c < 8; ++c) {
            int k = kbase + (tx << 3) + c;
            float e2k = e2f[k];
            #pragma unroll
            for (int r = 0; r < 4; ++r) {
                float md = (float)acc[r][c];
                float t  = __fmul_rn(2.0f, md);
                float A  = __fadd_rn(x2r[r], e2k);
                float s  = __fsub_rn(A, t);
                if (s < bestv[r]) { bestv[r] = s; besti[r] = k; }
            }
        }
    }
    #pragma unroll
    for (int r = 0; r < 4; ++r) {
        redv[(ty << 2) + r][tx] = bestv[r];
        redi[(ty << 2) + r][tx] = besti[r];
    }
    __syncthreads();
    if (tid < BM) {
        float bv = redv[tid][0]; int bi = redi[tid][0];
        #pragma unroll
        for (int t = 1; t < 16; ++t) {
            float v = redv[tid][t]; int i2 = redi[tid][t];
            if (v < bv || (v == bv && i2 < bi)) { bv = v; bi = i2; }
        }
        int grow = rowbase + tid;
        pv[(size_t)grow * KSLICES + kslice] = bv;
        pi[(size_t)grow * KSLICES + kslice] = bi;
    }
}

// ---- reduce split-K partials -> enc_idx + histogram ----
__global__ void argmin_reduce(const float* __restrict__ pv, const int* __restrict__ pi,
                              int* __restrict__ idxbuf, float* __restrict__ out_idx,
                              unsigned* __restrict__ counts) {
    int n = blockIdx.x * 256 + threadIdx.x;
    const float* v = &pv[(size_t)n * KSLICES];
    const int* ii = &pi[(size_t)n * KSLICES];
    float bv = v[0]; int bi = ii[0];
    #pragma unroll
    for (int s = 1; s < KSLICES; ++s) {
        float vv = v[s]; int i2 = ii[s];
        if (vv < bv || (vv == bv && i2 < bi)) { bv = vv; bi = i2; }
    }
    idxbuf[n] = bi;
    out_idx[n] = (float)bi;
    atomicAdd(&counts[bi], 1u);
}

// ---- gather quantized + straight-through + loss partials ----
__global__ void quant_loss_kernel(const float* __restrict__ x, const float* __restrict__ e,
                                  const int* __restrict__ idxbuf,
                                  float* __restrict__ qout, double* __restrict__ loss_part) {
    int n = blockIdx.x;
    int k = idxbuf[n];
    double part = 0.0;
    for (int d = threadIdx.x; d < D_; d += 256) {
        float q = e[(size_t)d * K_ + k];
        float xv = x[(size_t)n * D_ + d];
        float df = q - xv;
        qout[(size_t)n * D_ + d] = xv + df;
        part = fma((double)df, (double)df, part);
    }
    __shared__ double sr[256];
    sr[threadIdx.x] = part;
    __syncthreads();
    for (int s = 128; s > 0; s >>= 1) {
        if (threadIdx.x < s) sr[threadIdx.x] += sr[threadIdx.x + s];
        __syncthreads();
    }
    if (threadIdx.x == 0) loss_part[n] = sr[0];
}

// ---- new_un = 0.9*un, then scatter 0.1*x ----
__global__ void un_init_kernel(const float* __restrict__ un, float* __restrict__ out_un) {
    size_t i = ((size_t)blockIdx.x * 256 + threadIdx.x) * 4;
    float4 v = *(const float4*)(&un[i]);
    v.x *= 0.9f; v.y *= 0.9f; v.z *= 0.9f; v.w *= 0.9f;
    *(float4*)(&out_un[i]) = v;
}

__global__ void un_scatter_kernel(const float* __restrict__ x, const int* __restrict__ idxbuf,
                                  float* __restrict__ out_un) {
    int n = blockIdx.x;
    int k = idxbuf[n];
    for (int d = threadIdx.x; d < D_; d += 256) {
        atomicAdd(&out_un[(size_t)d * K_ + k], 0.1f * x[(size_t)n * D_ + d]);
    }
}

// ---- new_cs + perplexity partials ----
__global__ void cs_kernel(const unsigned* __restrict__ counts, const float* __restrict__ cs,
                          float* __restrict__ out_cs,
                          double* __restrict__ ncs_part, double* __restrict__ ent_part) {
    int tid = threadIdx.x;
    int k = blockIdx.x * 256 + tid;
    float cnt = (float)counts[k];
    float ncs = 0.1f * cnt + 0.9f * cs[k];
    out_cs[k] = ncs;
    double p = (double)counts[k] / 8192.0;
    double ent = -p * log(p + 1e-20);

    __shared__ double s1[256], s2[256];
    s1[tid] = (double)ncs;
    s2[tid] = ent;
    __syncthreads();
    for (int s = 128; s > 0; s >>= 1) {
        if (tid < s) { s1[tid] += s1[tid + s]; s2[tid] += s2[tid + s]; }
        __syncthreads();
    }
    if (tid == 0) { ncs_part[blockIdx.x] = s1[0]; ent_part[blockIdx.x] = s2[0]; }
}

// ---- loss, perplexity, nsum ----
__global__ void scalars_kernel(const double* __restrict__ loss_part,
                               const double* __restrict__ ncs_part,
                               const double* __restrict__ ent_part,
                               float* __restrict__ out_loss, float* __restrict__ out_ppl,
                               double* __restrict__ nsum_out) {
    __shared__ double sr[256];
    double s = 0.0;
    for (int i = threadIdx.x; i < N_; i += 256) s += loss_part[i];
    sr[threadIdx.x] = s;
    __syncthreads();
    for (int t = 128; t > 0; t >>= 1) {
        if (threadIdx.x < t) sr[threadIdx.x] += sr[threadIdx.x + t];
        __syncthreads();
    }
    if (threadIdx.x == 0) {
        out_loss[0] = (float)(0.25 * (sr[0] / (double)((size_t)N_ * D_)));
        double nsum = 0.0, ent = 0.0;
        for (int i = 0; i < 32; ++i) { nsum += ncs_part[i]; ent += ent_part[i]; }
        out_ppl[0] = (float)exp(ent);
        nsum_out[0] = nsum;
    }
}

// ---- new_e = new_un / stable_cs ----
__global__ void newe_kernel(const float* __restrict__ out_un, const float* __restrict__ out_cs,
                            const double* __restrict__ nsum, float* __restrict__ out_e) {
    size_t i = ((size_t)blockIdx.x * 256 + threadIdx.x) * 4;
    int k = (int)(i & (K_ - 1));
    double n = nsum[0];
    double denom = n + 8192.0 * 1e-20;
    float4 u = *(const float4*)(&out_un[i]);
    float4 c = *(const float4*)(&out_cs[k]);
    float4 r;
    r.x = u.x / (float)(((double)c.x + 1e-20) / denom * n);
    r.y = u.y / (float)(((double)c.y + 1e-20) / denom * n);
    r.z = u.z / (float)(((double)c.z + 1e-20) / denom * n);
    r.w = u.w / (float)(((double)c.w + 1e-20) / denom * n);
    *(float4*)(&out_e[i]) = r;
}

extern "C" void kernel_launch(void* const* d_in, const int* in_sizes, int n_in,
                              void* d_out, int out_size, void* d_ws, size_t ws_size,
                              hipStream_t stream) {
    const float* x  = (const float*)d_in[0];
    const float* e  = (const float*)d_in[1];
    const float* cs = (const float*)d_in[2];
    const float* un = (const float*)d_in[3];

    float* out = (float*)d_out;
    float* out_q    = out;                    // 4194304
    float* out_loss = out + 4194304;          // 1
    float* out_ppl  = out + 4194305;          // 1
    float* out_idx  = out + 4194306;          // 8192
    float* out_e    = out + 4202498;          // 4194304
    float* out_cs   = out + 8396802;          // 8192
    float* out_un   = out + 8404994;          // 4194304

    char* ws = (char*)d_ws;
    unsigned* counts  = (unsigned*)ws;                 // 32768 B  [zeroed]
    float* x2f        = (float*)(ws + 32768);          // 32768 B
    float* e2f        = (float*)(ws + 65536);          // 32768 B
    float* pv         = (float*)(ws + 98304);          // 262144 B
    int*   pi         = (int*)(ws + 360448);           // 262144 B
    int*   idxbuf     = (int*)(ws + 622592);           // 32768 B
    double* loss_part = (double*)(ws + 655360);        // 65536 B
    double* ncs_part  = (double*)(ws + 720896);        // 256 B
    double* ent_part  = (double*)(ws + 721152);        // 256 B
    double* nsum      = (double*)(ws + 721408);        // 8 B

    hipMemsetAsync(d_ws, 0, 32768, stream);
    x2_kernel<<<N_ / 256, 256, 0, stream>>>(x, x2f);
    e2f_kernel<<<K_ / 256, 256, 0, stream>>>(e, e2f);
    argmin_kernel<<<dim3(KSLICES, N_ / BM), 256, 0, stream>>>(x, e, x2f, e2f, pv, pi);
    argmin_reduce<<<N_ / 256, 256, 0, stream>>>(pv, pi, idxbuf, out_idx, counts);
    quant_loss_kernel<<<N_, 256, 0, stream>>>(x, e, idxbuf, out_q, loss_part);
    un_init_kernel<<<4096, 256, 0, stream>>>(un, out_un);
    un_scatter_kernel<<<N_, 256, 0, stream>>>(x, idxbuf, out_un);
    cs_kernel<<<K_ / 256, 256, 0, stream>>>(counts, cs, out_cs, ncs_part, ent_part);
    scalars_kernel<<<1, 256, 0, stream>>>(loss_part, ncs_part, ent_part, out_loss, out_ppl, nsum);
    newe_kernel<<<4096, 256, 0, stream>>>(out_un, out_cs, nsum, out_e);
}

// Round 4
// 1495.401 us; speedup vs baseline: 1.2454x; 1.2454x over previous
//
#include <hip/hip_runtime.h>
#include <math.h>

#define D_ 512
#define K_ 8192
#define N_ 8192

#define BM 128
#define BN 128
#define DK 32
#define KSLICES 8
#define KSL (K_ / KSLICES)   // 1024
#define TAU 4e-3f

// ---- x2[n] = np.sum(x*x, axis=1) replicated: numpy pairwise f32 ----
__global__ void x2_kernel(const float* __restrict__ x, float* __restrict__ x2f) {
    int n = blockIdx.x * 256 + threadIdx.x;
    const float* row = &x[(size_t)n * D_];
    float b[4];
    #pragma unroll
    for (int blk = 0; blk < 4; ++blk) {
        const float* a = row + blk * 128;
        float r[8];
        #pragma unroll
        for (int j = 0; j < 8; ++j) { float v = a[j]; r[j] = __fmul_rn(v, v); }
        for (int i = 8; i < 128; i += 8) {
            #pragma unroll
            for (int j = 0; j < 8; ++j) {
                float v = a[i + j];
                r[j] = __fadd_rn(r[j], __fmul_rn(v, v));
            }
        }
        b[blk] = __fadd_rn(__fadd_rn(__fadd_rn(r[0], r[1]), __fadd_rn(r[2], r[3])),
                           __fadd_rn(__fadd_rn(r[4], r[5]), __fadd_rn(r[6], r[7])));
    }
    x2f[n] = __fadd_rn(__fadd_rn(b[0], b[1]), __fadd_rn(b[2], b[3]));
}

// ---- e2[k] = np.sum(e*e, axis=0) replicated: sequential f32 over d ----
__global__ void e2f_kernel(const float* __restrict__ e, float* __restrict__ e2f) {
    int k = blockIdx.x * 256 + threadIdx.x;
    float s = 0.0f;
    for (int d = 0; d < D_; ++d) {
        float v = e[(size_t)d * K_ + k];
        s = __fadd_rn(s, __fmul_rn(v, v));
    }
    e2f[k] = s;
}

// ---- fast f32 distance pass: per-row (best, idx, second-best) per K-slice ----
__launch_bounds__(256, 2)
__global__ void argmin_fast(const float* __restrict__ x, const float* __restrict__ e,
                            const float* __restrict__ x2f, const float* __restrict__ e2f,
                            float* __restrict__ pv, int* __restrict__ pi,
                            float* __restrict__ psec) {
    __shared__ float smem[2 * DK * (BN + 4)];   // 33792 B, aliased for reduction
    float (*xs)[BN + 4] = (float(*)[BN + 4])smem;                    // [32][132] transposed x
    float (*es)[BN + 4] = (float(*)[BN + 4])(smem + DK * (BN + 4));  // [32][132]

    const int tid = threadIdx.x;
    const int tx = tid & 15, ty = tid >> 4;
    const int rowbase = blockIdx.y * BM;
    const int kslice = blockIdx.x;
    const int ksbase = kslice * KSL;

    float x2r[8];
    #pragma unroll
    for (int r = 0; r < 8; ++r) x2r[r] = x2f[rowbase + (ty << 3) + r];

    float bestv[8], secv[8];
    int besti[8];
    #pragma unroll
    for (int r = 0; r < 8; ++r) { bestv[r] = 3.0e38f; secv[r] = 3.0e38f; besti[r] = 0; }

    for (int kt = 0; kt < KSL / BN; ++kt) {
        const int kbase = ksbase + kt * BN;
        float acc[8][8];
        #pragma unroll
        for (int r = 0; r < 8; ++r)
            #pragma unroll
            for (int c = 0; c < 8; ++c)
                acc[r][c] = 0.0f;

        for (int d0 = 0; d0 < D_; d0 += DK) {
            #pragma unroll
            for (int j = 0; j < 4; ++j) {
                int i = tid + j * 256;          // 0..1023
                int r = i >> 3;                 // 0..127
                int dq = (i & 7) << 2;          // 0..28
                const float4 v = *(const float4*)(&x[(size_t)(rowbase + r) * D_ + d0 + dq]);
                xs[dq + 0][r] = v.x; xs[dq + 1][r] = v.y;
                xs[dq + 2][r] = v.z; xs[dq + 3][r] = v.w;
            }
            #pragma unroll
            for (int j = 0; j < 4; ++j) {
                int i = tid + j * 256;          // 0..1023
                int dd = i >> 5;                // 0..31
                int c4 = (i & 31) << 2;         // 0..124
                *(float4*)(&es[dd][c4]) = *(const float4*)(&e[(size_t)(d0 + dd) * K_ + kbase + c4]);
            }
            __syncthreads();
            #pragma unroll
            for (int dk = 0; dk < DK; ++dk) {
                const float4 xa = *(const float4*)(&xs[dk][ty << 3]);
                const float4 xb = *(const float4*)(&xs[dk][(ty << 3) + 4]);
                const float4 ea = *(const float4*)(&es[dk][tx << 3]);
                const float4 eb = *(const float4*)(&es[dk][(tx << 3) + 4]);
                const float xr[8] = {xa.x, xa.y, xa.z, xa.w, xb.x, xb.y, xb.z, xb.w};
                const float ec[8] = {ea.x, ea.y, ea.z, ea.w, eb.x, eb.y, eb.z, eb.w};
                #pragma unroll
                for (int r = 0; r < 8; ++r)
                    #pragma unroll
                    for (int c = 0; c < 8; ++c)
                        acc[r][c] = fmaf(xr[r], ec[c], acc[r][c]);
            }
            __syncthreads();
        }
        // replicated-f32 score; track best + second-best (k ascending per thread)
        #pragma unroll
        for (int c = 0; c < 8; ++c) {
            int k = kbase + (tx << 3) + c;
            float e2k = e2f[k];
            #pragma unroll
            for (int r = 0; r < 8; ++r) {
                float t = __fmul_rn(2.0f, acc[r][c]);
                float A = __fadd_rn(x2r[r], e2k);
                float s = __fsub_rn(A, t);
                if (s < bestv[r]) { secv[r] = bestv[r]; bestv[r] = s; besti[r] = k; }
                else if (s < secv[r]) secv[r] = s;
            }
        }
    }
    __syncthreads();
    float (*redv)[16] = (float(*)[16])smem;          // [128][16]
    int   (*redi)[16] = (int(*)[16])(smem + 2048);
    float (*reds)[16] = (float(*)[16])(smem + 4096);
    #pragma unroll
    for (int r = 0; r < 8; ++r) {
        redv[(ty << 3) + r][tx] = bestv[r];
        redi[(ty << 3) + r][tx] = besti[r];
        reds[(ty << 3) + r][tx] = secv[r];
    }
    __syncthreads();
    if (tid < BM) {
        float bv = redv[tid][0]; int bi = redi[tid][0]; float sv = reds[tid][0];
        #pragma unroll
        for (int t = 1; t < 16; ++t) {
            float v = redv[tid][t]; int i2 = redi[tid][t]; float s2 = reds[tid][t];
            if (v < bv || (v == bv && i2 < bi)) {
                sv = fminf(fminf(sv, s2), bv);
                bv = v; bi = i2;
            } else {
                sv = fminf(sv, v);
            }
        }
        int grow = rowbase + tid;
        pv[(size_t)grow * KSLICES + kslice] = bv;
        pi[(size_t)grow * KSLICES + kslice] = bi;
        psec[(size_t)grow * KSLICES + kslice] = sv;
    }
}

// ---- reduce split-K partials -> enc_idx; flag ambiguous rows ----
__global__ void argmin_reduce(const float* __restrict__ pv, const int* __restrict__ pi,
                              const float* __restrict__ psec,
                              int* __restrict__ idxbuf, float* __restrict__ out_idx,
                              int* __restrict__ flaglist, unsigned* __restrict__ nflag) {
    int n = blockIdx.x * 256 + threadIdx.x;
    float bv = 3.0e38f, sv = 3.0e38f; int bi = 0x7fffffff;
    #pragma unroll
    for (int s = 0; s < KSLICES; ++s) {
        float vv = pv[(size_t)n * KSLICES + s];
        int   ii = pi[(size_t)n * KSLICES + s];
        float ss = psec[(size_t)n * KSLICES + s];
        if (vv < bv || (vv == bv && ii < bi)) {
            sv = fminf(fminf(sv, ss), bv);
            bv = vv; bi = ii;
        } else {
            sv = fminf(sv, vv);
        }
    }
    idxbuf[n] = bi;
    out_idx[n] = (float)bi;
    if (sv - bv < TAU) {
        unsigned pos = atomicAdd(nflag, 1u);
        flaglist[pos] = n;
    }
}

// ---- exact f64 refine of flagged rows (round-3 proven semantics) ----
__launch_bounds__(256, 2)
__global__ void refine_kernel(const float* __restrict__ x, const float* __restrict__ e,
                              const float* __restrict__ x2f, const float* __restrict__ e2f,
                              const int* __restrict__ flaglist, const unsigned* __restrict__ nflag,
                              int* __restrict__ idxbuf, float* __restrict__ out_idx) {
    __shared__ float xrow[D_];
    __shared__ float redv[256];
    __shared__ int   redi[256];
    const int tid = threadIdx.x;
    const unsigned nf = *nflag;
    for (unsigned f = blockIdx.x; f < nf; f += gridDim.x) {
        const int n = flaglist[f];
        __syncthreads();
        for (int d = tid; d < D_; d += 256) xrow[d] = x[(size_t)n * D_ + d];
        __syncthreads();
        const float x2 = x2f[n];
        float bv = 3.0e38f; int bi = 0x7fffffff;
        for (int j = 0; j < 8; ++j) {
            const int k0 = (tid << 2) + j * 1024;
            double a0 = 0.0, a1 = 0.0, a2 = 0.0, a3 = 0.0;
            #pragma unroll 4
            for (int d = 0; d < D_; ++d) {
                const float4 ev = *(const float4*)(&e[(size_t)d * K_ + k0]);
                const double xd = (double)xrow[d];
                a0 = fma(xd, (double)ev.x, a0);
                a1 = fma(xd, (double)ev.y, a1);
                a2 = fma(xd, (double)ev.z, a2);
                a3 = fma(xd, (double)ev.w, a3);
            }
            double accs[4] = {a0, a1, a2, a3};
            #pragma unroll
            for (int c = 0; c < 4; ++c) {
                const int k = k0 + c;
                float md = (float)accs[c];
                float s = __fsub_rn(__fadd_rn(x2, e2f[k]), __fmul_rn(2.0f, md));
                if (s < bv || (s == bv && k < bi)) { bv = s; bi = k; }
            }
        }
        redv[tid] = bv; redi[tid] = bi;
        __syncthreads();
        for (int s2 = 128; s2 > 0; s2 >>= 1) {
            if (tid < s2) {
                float v2 = redv[tid + s2]; int i2 = redi[tid + s2];
                if (v2 < redv[tid] || (v2 == redv[tid] && i2 < redi[tid])) {
                    redv[tid] = v2; redi[tid] = i2;
                }
            }
            __syncthreads();
        }
        if (tid == 0) { idxbuf[n] = redi[0]; out_idx[n] = (float)redi[0]; }
    }
}

// ---- histogram after refine ----
__global__ void counts_kernel(const int* __restrict__ idxbuf, unsigned* __restrict__ counts) {
    int n = blockIdx.x * 256 + threadIdx.x;
    atomicAdd(&counts[idxbuf[n]], 1u);
}

// ---- gather quantized + straight-through + loss partials ----
__global__ void quant_loss_kernel(const float* __restrict__ x, const float* __restrict__ e,
                                  const int* __restrict__ idxbuf,
                                  float* __restrict__ qout, double* __restrict__ loss_part) {
    int n = blockIdx.x;
    int k = idxbuf[n];
    double part = 0.0;
    for (int d = threadIdx.x; d < D_; d += 256) {
        float q = e[(size_t)d * K_ + k];
        float xv = x[(size_t)n * D_ + d];
        float df = q - xv;
        qout[(size_t)n * D_ + d] = xv + df;
        part = fma((double)df, (double)df, part);
    }
    __shared__ double sr[256];
    sr[threadIdx.x] = part;
    __syncthreads();
    for (int s = 128; s > 0; s >>= 1) {
        if (threadIdx.x < s) sr[threadIdx.x] += sr[threadIdx.x + s];
        __syncthreads();
    }
    if (threadIdx.x == 0) loss_part[n] = sr[0];
}

// ---- new_un = 0.9*un, then scatter 0.1*x ----
__global__ void un_init_kernel(const float* __restrict__ un, float* __restrict__ out_un) {
    size_t i = ((size_t)blockIdx.x * 256 + threadIdx.x) * 4;
    float4 v = *(const float4*)(&un[i]);
    v.x *= 0.9f; v.y *= 0.9f; v.z *= 0.9f; v.w *= 0.9f;
    *(float4*)(&out_un[i]) = v;
}

__global__ void un_scatter_kernel(const float* __restrict__ x, const int* __restrict__ idxbuf,
                                  float* __restrict__ out_un) {
    int n = blockIdx.x;
    int k = idxbuf[n];
    for (int d = threadIdx.x; d < D_; d += 256) {
        atomicAdd(&out_un[(size_t)d * K_ + k], 0.1f * x[(size_t)n * D_ + d]);
    }
}

// ---- new_cs + perplexity partials ----
__global__ void cs_kernel(const unsigned* __restrict__ counts, const float* __restrict__ cs,
                          float* __restrict__ out_cs,
                          double* __restrict__ ncs_part, double* __restrict__ ent_part) {
    int tid = threadIdx.x;
    int k = blockIdx.x * 256 + tid;
    float cnt = (float)counts[k];
    float ncs = 0.1f * cnt + 0.9f * cs[k];
    out_cs[k] = ncs;
    double p = (double)counts[k] / 8192.0;
    double ent = -p * log(p + 1e-20);

    __shared__ double s1[256], s2[256];
    s1[tid] = (double)ncs;
    s2[tid] = ent;
    __syncthreads();
    for (int s = 128; s > 0; s >>= 1) {
        if (tid < s) { s1[tid] += s1[tid + s]; s2[tid] += s2[tid + s]; }
        __syncthreads();
    }
    if (tid == 0) { ncs_part[blockIdx.x] = s1[0]; ent_part[blockIdx.x] = s2[0]; }
}

// ---- loss, perplexity, nsum ----
__global__ void scalars_kernel(const double* __restrict__ loss_part,
                               const double* __restrict__ ncs_part,
                               const double* __restrict__ ent_part,
                               float* __restrict__ out_loss, float* __restrict__ out_ppl,
                               double* __restrict__ nsum_out) {
    __shared__ double sr[256];
    double s = 0.0;
    for (int i = threadIdx.x; i < N_; i += 256) s += loss_part[i];
    sr[threadIdx.x] = s;
    __syncthreads();
    for (int t = 128; t > 0; t >>= 1) {
        if (threadIdx.x < t) sr[threadIdx.x] += sr[threadIdx.x + t];
        __syncthreads();
    }
    if (threadIdx.x == 0) {
        out_loss[0] = (float)(0.25 * (sr[0] / (double)((size_t)N_ * D_)));
        double nsum = 0.0, ent = 0.0;
        for (int i = 0; i < 32; ++i) { nsum += ncs_part[i]; ent += ent_part[i]; }
        out_ppl[0] = (float)exp(ent);
        nsum_out[0] = nsum;
    }
}

// ---- new_e = new_un / stable_cs ----
__global__ void newe_kernel(const float* __restrict__ out_un, const float* __restrict__ out_cs,
                            const double* __restrict__ nsum, float* __restrict__ out_e) {
    size_t i = ((size_t)blockIdx.x * 256 + threadIdx.x) * 4;
    int k = (int)(i & (K_ - 1));
    double n = nsum[0];
    double denom = n + 8192.0 * 1e-20;
    float4 u = *(const float4*)(&out_un[i]);
    float4 c = *(const float4*)(&out_cs[k]);
    float4 r;
    r.x = u.x / (float)(((double)c.x + 1e-20) / denom * n);
    r.y = u.y / (float)(((double)c.y + 1e-20) / denom * n);
    r.z = u.z / (float)(((double)c.z + 1e-20) / denom * n);
    r.w = u.w / (float)(((double)c.w + 1e-20) / denom * n);
    *(float4*)(&out_e[i]) = r;
}

extern "C" void kernel_launch(void* const* d_in, const int* in_sizes, int n_in,
                              void* d_out, int out_size, void* d_ws, size_t ws_size,
                              hipStream_t stream) {
    const float* x  = (const float*)d_in[0];
    const float* e  = (const float*)d_in[1];
    const float* cs = (const float*)d_in[2];
    const float* un = (const float*)d_in[3];

    float* out = (float*)d_out;
    float* out_q    = out;                    // 4194304
    float* out_loss = out + 4194304;          // 1
    float* out_ppl  = out + 4194305;          // 1
    float* out_idx  = out + 4194306;          // 8192
    float* out_e    = out + 4202498;          // 4194304
    float* out_cs   = out + 8396802;          // 8192
    float* out_un   = out + 8404994;          // 4194304

    char* ws = (char*)d_ws;
    unsigned* counts  = (unsigned*)ws;                 // 32768 B  [zeroed]
    unsigned* nflag   = (unsigned*)(ws + 32768);       // 256 B    [zeroed]
    float* x2f        = (float*)(ws + 36864);          // 32768 B
    float* e2f        = (float*)(ws + 69632);          // 32768 B
    float* pv         = (float*)(ws + 102400);         // 262144 B
    int*   pi         = (int*)(ws + 364544);           // 262144 B
    float* psec       = (float*)(ws + 626688);         // 262144 B
    int*   idxbuf     = (int*)(ws + 888832);           // 32768 B
    int*   flaglist   = (int*)(ws + 921600);           // 32768 B
    double* loss_part = (double*)(ws + 954368);        // 65536 B
    double* ncs_part  = (double*)(ws + 1019904);       // 256 B
    double* ent_part  = (double*)(ws + 1020160);       // 256 B
    double* nsum      = (double*)(ws + 1020416);       // 8 B

    hipMemsetAsync(d_ws, 0, 36864, stream);
    x2_kernel<<<N_ / 256, 256, 0, stream>>>(x, x2f);
    e2f_kernel<<<K_ / 256, 256, 0, stream>>>(e, e2f);
    argmin_fast<<<dim3(KSLICES, N_ / BM), 256, 0, stream>>>(x, e, x2f, e2f, pv, pi, psec);
    argmin_reduce<<<N_ / 256, 256, 0, stream>>>(pv, pi, psec, idxbuf, out_idx, flaglist, nflag);
    refine_kernel<<<64, 256, 0, stream>>>(x, e, x2f, e2f, flaglist, nflag, idxbuf, out_idx);
    counts_kernel<<<N_ / 256, 256, 0, stream>>>(idxbuf, counts);
    quant_loss_kernel<<<N_, 256, 0, stream>>>(x, e, idxbuf, out_q, loss_part);
    un_init_kernel<<<4096, 256, 0, stream>>>(un, out_un);
    un_scatter_kernel<<<N_, 256, 0, stream>>>(x, idxbuf, out_un);
    cs_kernel<<<K_ / 256, 256, 0, stream>>>(counts, cs, out_cs, ncs_part, ent_part);
    scalars_kernel<<<1, 256, 0, stream>>>(loss_part, ncs_part, ent_part, out_loss, out_ppl, nsum);
    newe_kernel<<<4096, 256, 0, stream>>>(out_un, out_cs, nsum, out_e);
}

// Round 5
// 922.694 us; speedup vs baseline: 2.0185x; 1.6207x over previous
//
#include <hip/hip_runtime.h>
#include <math.h>

#define D_ 512
#define K_ 8192
#define N_ 8192
#define KSLICES 8
#define TAU 2.5e-3f

typedef __attribute__((ext_vector_type(8))) short bf16x8;
typedef __attribute__((ext_vector_type(8))) unsigned short u16x8;
typedef __attribute__((ext_vector_type(4))) float f32x4;

__device__ __forceinline__ unsigned short bf16_rne(float f) {
    unsigned u = __float_as_uint(f);
    unsigned r = (u + 0x7fffu + ((u >> 16) & 1u)) >> 16;
    return (unsigned short)r;
}
__device__ __forceinline__ float bf16_to_f(unsigned short h) {
    return __uint_as_float(((unsigned)h) << 16);
}

// ---- x2[n] = np.sum(x*x, axis=1) replicated: numpy pairwise f32 ----
__global__ void x2_kernel(const float* __restrict__ x, float* __restrict__ x2f) {
    int n = blockIdx.x * 256 + threadIdx.x;
    const float* row = &x[(size_t)n * D_];
    float b[4];
    #pragma unroll
    for (int blk = 0; blk < 4; ++blk) {
        const float* a = row + blk * 128;
        float r[8];
        #pragma unroll
        for (int j = 0; j < 8; ++j) { float v = a[j]; r[j] = __fmul_rn(v, v); }
        for (int i = 8; i < 128; i += 8) {
            #pragma unroll
            for (int j = 0; j < 8; ++j) {
                float v = a[i + j];
                r[j] = __fadd_rn(r[j], __fmul_rn(v, v));
            }
        }
        b[blk] = __fadd_rn(__fadd_rn(__fadd_rn(r[0], r[1]), __fadd_rn(r[2], r[3])),
                           __fadd_rn(__fadd_rn(r[4], r[5]), __fadd_rn(r[6], r[7])));
    }
    x2f[n] = __fadd_rn(__fadd_rn(b[0], b[1]), __fadd_rn(b[2], b[3]));
}

// ---- e2[k] = np.sum(e*e, axis=0) replicated: sequential f32 over d ----
__global__ void e2f_kernel(const float* __restrict__ e, float* __restrict__ e2f) {
    int k = blockIdx.x * 256 + threadIdx.x;
    float s = 0.0f;
    for (int d = 0; d < D_; ++d) {
        float v = e[(size_t)d * K_ + k];
        s = __fadd_rn(s, __fmul_rn(v, v));
    }
    e2f[k] = s;
}

// ---- split x into bf16 hi/lo, same [N][D] layout ----
__global__ void xsplit_kernel(const float* __restrict__ x,
                              unsigned short* __restrict__ xh, unsigned short* __restrict__ xl) {
    size_t i = ((size_t)blockIdx.x * 256 + threadIdx.x) * 4;
    float4 v = *(const float4*)&x[i];
    ushort4 h, l;
    h.x = bf16_rne(v.x); l.x = bf16_rne(__fsub_rn(v.x, bf16_to_f(h.x)));
    h.y = bf16_rne(v.y); l.y = bf16_rne(__fsub_rn(v.y, bf16_to_f(h.y)));
    h.z = bf16_rne(v.z); l.z = bf16_rne(__fsub_rn(v.z, bf16_to_f(h.z)));
    h.w = bf16_rne(v.w); l.w = bf16_rne(__fsub_rn(v.w, bf16_to_f(h.w)));
    *(ushort4*)&xh[i] = h;
    *(ushort4*)&xl[i] = l;
}

// ---- split e into bf16 hi/lo TRANSPOSED: ehT/elT are [K][D] ----
__global__ void esplitT_kernel(const float* __restrict__ e,
                               unsigned short* __restrict__ ehT, unsigned short* __restrict__ elT) {
    __shared__ float t[64][65];
    const int tid = threadIdx.x;
    const int k0 = blockIdx.x * 64;
    const int d0 = blockIdx.y * 64;
    #pragma unroll
    for (int it = 0; it < 4; ++it) {
        int dt = (tid >> 4) + it * 16;
        int c4 = (tid & 15) * 4;
        float4 v = *(const float4*)&e[(size_t)(d0 + dt) * K_ + k0 + c4];
        t[dt][c4 + 0] = v.x; t[dt][c4 + 1] = v.y; t[dt][c4 + 2] = v.z; t[dt][c4 + 3] = v.w;
    }
    __syncthreads();
    const int m = tid >> 2, ch = tid & 3;
    u16x8 h0, h1, l0, l1;
    #pragma unroll
    for (int j = 0; j < 8; ++j) {
        float f = t[ch * 16 + j][m];
        unsigned short hh = bf16_rne(f);
        h0[j] = hh; l0[j] = bf16_rne(__fsub_rn(f, bf16_to_f(hh)));
    }
    #pragma unroll
    for (int j = 0; j < 8; ++j) {
        float f = t[ch * 16 + 8 + j][m];
        unsigned short hh = bf16_rne(f);
        h1[j] = hh; l1[j] = bf16_rne(__fsub_rn(f, bf16_to_f(hh)));
    }
    size_t o = (size_t)(k0 + m) * D_ + d0 + ch * 16;
    *(u16x8*)&ehT[o] = h0; *(u16x8*)&ehT[o + 8] = h1;
    *(u16x8*)&elT[o] = l0; *(u16x8*)&elT[o + 8] = l1;
}

// ---- MFMA bf16-split distance pass: per-row (best, idx, second) per K-slice ----
// Block: 128 rows x (1024 codes as 8 chunks of 128). 4 waves in 2x2 (wm codes, wn rows).
__launch_bounds__(256, 2)
__global__ void argmin_mfma(const unsigned short* __restrict__ xh, const unsigned short* __restrict__ xl,
                            const unsigned short* __restrict__ ehT, const unsigned short* __restrict__ elT,
                            const float* __restrict__ x2f, const float* __restrict__ e2f,
                            float* __restrict__ pv, int* __restrict__ pi, float* __restrict__ psec) {
    __shared__ unsigned short smem[2][4][4096];  // [buf][xh,xl,eh,el][128 rows * 32 dims]
    __shared__ float e2s[128];

    const int tid = threadIdx.x;
    const int lane = tid & 63;
    const int wid = tid >> 6;
    const int wm = wid & 1, wn = wid >> 1;
    const int lidx = lane & 15, g = lane >> 4;
    const int rowbase = blockIdx.y * 128;
    const int kslice = blockIdx.x;

    float x2r[4];
    #pragma unroll
    for (int nt = 0; nt < 4; ++nt)
        x2r[nt] = x2f[rowbase + (wn << 6) + (nt << 4) + lidx];

    float best[4], sec[4]; int bi[4];
    #pragma unroll
    for (int nt = 0; nt < 4; ++nt) { best[nt] = 3.0e38f; sec[nt] = 3.0e38f; bi[nt] = 0; }

    // staging map: thread handles flat chunks f0, f1; row = f>>2, slot s = f&3,
    // source 16B-chunk c = (s - (row>>1)) & 3  (slot rotation -> 2-way banks on read)
    const int f0 = tid,        r0 = f0 >> 2, s0 = f0 & 3, c0 = (s0 - (r0 >> 1)) & 3;
    const int f1 = tid + 256,  r1 = f1 >> 2, s1 = f1 & 3, c1 = (s1 - (r1 >> 1)) & 3;
    const size_t xo0 = (size_t)(rowbase + r0) * D_ + c0 * 8;
    const size_t xo1 = (size_t)(rowbase + r1) * D_ + c1 * 8;

    for (int cc = 0; cc < 8; ++cc) {
        const int codebase = kslice * 1024 + cc * 128;
        __syncthreads();
        if (tid < 128) e2s[tid] = e2f[codebase + tid];
        const size_t eo0 = (size_t)(codebase + r0) * D_ + c0 * 8;
        const size_t eo1 = (size_t)(codebase + r1) * D_ + c1 * 8;

        f32x4 acc_hi[4][4], acc_md[4][4];
        const f32x4 z4 = {0.0f, 0.0f, 0.0f, 0.0f};
        #pragma unroll
        for (int mt = 0; mt < 4; ++mt)
            #pragma unroll
            for (int nt = 0; nt < 4; ++nt) { acc_hi[mt][nt] = z4; acc_md[mt][nt] = z4; }

        u16x8 st[8];
        // stage step 0 -> buf 0
        st[0] = *(const u16x8*)&xh[xo0]; st[1] = *(const u16x8*)&xl[xo0];
        st[2] = *(const u16x8*)&ehT[eo0]; st[3] = *(const u16x8*)&elT[eo0];
        st[4] = *(const u16x8*)&xh[xo1]; st[5] = *(const u16x8*)&xl[xo1];
        st[6] = *(const u16x8*)&ehT[eo1]; st[7] = *(const u16x8*)&elT[eo1];
        *(u16x8*)&smem[0][0][f0 * 8] = st[0]; *(u16x8*)&smem[0][1][f0 * 8] = st[1];
        *(u16x8*)&smem[0][2][f0 * 8] = st[2]; *(u16x8*)&smem[0][3][f0 * 8] = st[3];
        *(u16x8*)&smem[0][0][f1 * 8] = st[4]; *(u16x8*)&smem[0][1][f1 * 8] = st[5];
        *(u16x8*)&smem[0][2][f1 * 8] = st[6]; *(u16x8*)&smem[0][3][f1 * 8] = st[7];
        __syncthreads();

        for (int step = 0; step < 16; ++step) {
            const int cur = step & 1;
            if (step < 15) {   // prefetch next k-step while MFMAs run
                const int d0 = (step + 1) << 5;
                st[0] = *(const u16x8*)&xh[xo0 + d0]; st[1] = *(const u16x8*)&xl[xo0 + d0];
                st[2] = *(const u16x8*)&ehT[eo0 + d0]; st[3] = *(const u16x8*)&elT[eo0 + d0];
                st[4] = *(const u16x8*)&xh[xo1 + d0]; st[5] = *(const u16x8*)&xl[xo1 + d0];
                st[6] = *(const u16x8*)&ehT[eo1 + d0]; st[7] = *(const u16x8*)&elT[eo1 + d0];
            }
            const unsigned short* XH = smem[cur][0];
            const unsigned short* XL = smem[cur][1];
            const unsigned short* EH = smem[cur][2];
            const unsigned short* EL = smem[cur][3];
            bf16x8 bh[4], bl[4];
            #pragma unroll
            for (int nt = 0; nt < 4; ++nt) {
                int n = (wn << 6) + (nt << 4) + lidx;
                int sb = (g + (n >> 1)) & 3;
                bh[nt] = *(const bf16x8*)&XH[n * 32 + sb * 8];
                bl[nt] = *(const bf16x8*)&XL[n * 32 + sb * 8];
            }
            #pragma unroll
            for (int mt = 0; mt < 4; ++mt) {
                int m = (wm << 6) + (mt << 4) + lidx;
                int sa = (g + (m >> 1)) & 3;
                bf16x8 ah = *(const bf16x8*)&EH[m * 32 + sa * 8];
                bf16x8 al = *(const bf16x8*)&EL[m * 32 + sa * 8];
                #pragma unroll
                for (int nt = 0; nt < 4; ++nt) {
                    acc_hi[mt][nt] = __builtin_amdgcn_mfma_f32_16x16x32_bf16(ah, bh[nt], acc_hi[mt][nt], 0, 0, 0);
                    acc_md[mt][nt] = __builtin_amdgcn_mfma_f32_16x16x32_bf16(ah, bl[nt], acc_md[mt][nt], 0, 0, 0);
                    acc_md[mt][nt] = __builtin_amdgcn_mfma_f32_16x16x32_bf16(al, bh[nt], acc_md[mt][nt], 0, 0, 0);
                }
            }
            if (step < 15) {
                unsigned short* DXH = smem[cur ^ 1][0];
                unsigned short* DXL = smem[cur ^ 1][1];
                unsigned short* DEH = smem[cur ^ 1][2];
                unsigned short* DEL = smem[cur ^ 1][3];
                *(u16x8*)&DXH[f0 * 8] = st[0]; *(u16x8*)&DXL[f0 * 8] = st[1];
                *(u16x8*)&DEH[f0 * 8] = st[2]; *(u16x8*)&DEL[f0 * 8] = st[3];
                *(u16x8*)&DXH[f1 * 8] = st[4]; *(u16x8*)&DXL[f1 * 8] = st[5];
                *(u16x8*)&DEH[f1 * 8] = st[6]; *(u16x8*)&DEL[f1 * 8] = st[7];
            }
            __syncthreads();
        }

        // score this chunk: C row (code) = wm*64 + mt*16 + g*4 + r; col (x-row) = wn*64 + nt*16 + lidx
        #pragma unroll
        for (int mt = 0; mt < 4; ++mt) {
            #pragma unroll
            for (int r = 0; r < 4; ++r) {
                const int ml = (wm << 6) + (mt << 4) + (g << 2) + r;
                const float e2k = e2s[ml];
                const int kg = codebase + ml;
                #pragma unroll
                for (int nt = 0; nt < 4; ++nt) {
                    float dot = __fadd_rn(acc_hi[mt][nt][r], acc_md[mt][nt][r]);
                    float s = __fsub_rn(__fadd_rn(x2r[nt], e2k), __fmul_rn(2.0f, dot));
                    if (s < best[nt]) { sec[nt] = best[nt]; best[nt] = s; bi[nt] = kg; }
                    else if (s < sec[nt]) sec[nt] = s;
                }
            }
        }
    }

    // cross-lane merge over g (lanes ^16, ^32), then cross-wave (wm) merge via LDS
    __syncthreads();
    float* redB = (float*)&smem[0][0][0];
    float* redS = redB + 256;
    int*   redI = (int*)(redS + 256);
    #pragma unroll
    for (int nt = 0; nt < 4; ++nt) {
        #pragma unroll
        for (int off = 16; off < 64; off <<= 1) {
            float ov = __shfl_xor(best[nt], off);
            float os = __shfl_xor(sec[nt], off);
            int   oi = __shfl_xor(bi[nt], off);
            if (ov < best[nt] || (ov == best[nt] && oi < bi[nt])) {
                sec[nt] = fminf(best[nt], os);
                best[nt] = ov; bi[nt] = oi;
            } else {
                sec[nt] = fminf(sec[nt], ov);
            }
        }
        if (g == 0) {
            int rl = (wn << 6) + (nt << 4) + lidx;
            redB[rl * 2 + wm] = best[nt];
            redS[rl * 2 + wm] = sec[nt];
            redI[rl * 2 + wm] = bi[nt];
        }
    }
    __syncthreads();
    if (tid < 128) {
        float b0 = redB[tid * 2], b1 = redB[tid * 2 + 1];
        float q0 = redS[tid * 2], q1 = redS[tid * 2 + 1];
        int i0 = redI[tid * 2], i1 = redI[tid * 2 + 1];
        float bv, sv; int bx;
        if (b1 < b0 || (b1 == b0 && i1 < i0)) { bv = b1; bx = i1; sv = fminf(q1, b0); }
        else { bv = b0; bx = i0; sv = fminf(q0, b1); }
        int grow = rowbase + tid;
        pv[(size_t)grow * KSLICES + kslice] = bv;
        pi[(size_t)grow * KSLICES + kslice] = bx;
        psec[(size_t)grow * KSLICES + kslice] = sv;
    }
}

// ---- reduce split-K partials -> enc_idx; flag ambiguous rows ----
__global__ void argmin_reduce(const float* __restrict__ pv, const int* __restrict__ pi,
                              const float* __restrict__ psec,
                              int* __restrict__ idxbuf, float* __restrict__ out_idx,
                              int* __restrict__ flaglist, unsigned* __restrict__ nflag) {
    int n = blockIdx.x * 256 + threadIdx.x;
    float bv = 3.0e38f, sv = 3.0e38f; int bi = 0x7fffffff;
    #pragma unroll
    for (int s = 0; s < KSLICES; ++s) {
        float vv = pv[(size_t)n * KSLICES + s];
        int   ii = pi[(size_t)n * KSLICES + s];
        float ss = psec[(size_t)n * KSLICES + s];
        if (vv < bv || (vv == bv && ii < bi)) {
            sv = fminf(fminf(sv, ss), bv);
            bv = vv; bi = ii;
        } else {
            sv = fminf(sv, vv);
        }
    }
    idxbuf[n] = bi;
    out_idx[n] = (float)bi;
    if (sv - bv < TAU) {
        unsigned pos = atomicAdd(nflag, 1u);
        flaglist[pos] = n;
    }
}

// ---- exact f64 refine of flagged rows (np-replicated f32 scoring, proven R3) ----
__launch_bounds__(256, 2)
__global__ void refine_kernel(const float* __restrict__ x, const float* __restrict__ e,
                              const float* __restrict__ x2f, const float* __restrict__ e2f,
                              const int* __restrict__ flaglist, const unsigned* __restrict__ nflag,
                              int* __restrict__ idxbuf, float* __restrict__ out_idx) {
    __shared__ float xrow[D_];
    __shared__ float redv[256];
    __shared__ int   redi[256];
    const int tid = threadIdx.x;
    const unsigned nf = *nflag;
    for (unsigned f = blockIdx.x; f < nf; f += gridDim.x) {
        const int n = flaglist[f];
        __syncthreads();
        for (int d = tid; d < D_; d += 256) xrow[d] = x[(size_t)n * D_ + d];
        __syncthreads();
        const float x2 = x2f[n];
        float bv = 3.0e38f; int bi = 0x7fffffff;
        for (int j = 0; j < 8; ++j) {
            const int k0 = (tid << 2) + j * 1024;
            double a0 = 0.0, a1 = 0.0, a2 = 0.0, a3 = 0.0;
            #pragma unroll 4
            for (int d = 0; d < D_; ++d) {
                const float4 ev = *(const float4*)(&e[(size_t)d * K_ + k0]);
                const double xd = (double)xrow[d];
                a0 = fma(xd, (double)ev.x, a0);
                a1 = fma(xd, (double)ev.y, a1);
                a2 = fma(xd, (double)ev.z, a2);
                a3 = fma(xd, (double)ev.w, a3);
            }
            double accs[4] = {a0, a1, a2, a3};
            #pragma unroll
            for (int c = 0; c < 4; ++c) {
                const int k = k0 + c;
                float md = (float)accs[c];
                float s = __fsub_rn(__fadd_rn(x2, e2f[k]), __fmul_rn(2.0f, md));
                if (s < bv || (s == bv && k < bi)) { bv = s; bi = k; }
            }
        }
        redv[tid] = bv; redi[tid] = bi;
        __syncthreads();
        for (int s2 = 128; s2 > 0; s2 >>= 1) {
            if (tid < s2) {
                float v2 = redv[tid + s2]; int i2 = redi[tid + s2];
                if (v2 < redv[tid] || (v2 == redv[tid] && i2 < redi[tid])) {
                    redv[tid] = v2; redi[tid] = i2;
                }
            }
            __syncthreads();
        }
        if (tid == 0) { idxbuf[n] = redi[0]; out_idx[n] = (float)redi[0]; }
    }
}

// ---- histogram after refine ----
__global__ void counts_kernel(const int* __restrict__ idxbuf, unsigned* __restrict__ counts) {
    int n = blockIdx.x * 256 + threadIdx.x;
    atomicAdd(&counts[idxbuf[n]], 1u);
}

// ---- gather quantized + straight-through + loss partials ----
__global__ void quant_loss_kernel(const float* __restrict__ x, const float* __restrict__ e,
                                  const int* __restrict__ idxbuf,
                                  float* __restrict__ qout, double* __restrict__ loss_part) {
    int n = blockIdx.x;
    int k = idxbuf[n];
    double part = 0.0;
    for (int d = threadIdx.x; d < D_; d += 256) {
        float q = e[(size_t)d * K_ + k];
        float xv = x[(size_t)n * D_ + d];
        float df = q - xv;
        qout[(size_t)n * D_ + d] = xv + df;
        part = fma((double)df, (double)df, part);
    }
    __shared__ double sr[256];
    sr[threadIdx.x] = part;
    __syncthreads();
    for (int s = 128; s > 0; s >>= 1) {
        if (threadIdx.x < s) sr[threadIdx.x] += sr[threadIdx.x + s];
        __syncthreads();
    }
    if (threadIdx.x == 0) loss_part[n] = sr[0];
}

// ---- new_un = 0.9*un, then scatter 0.1*x ----
__global__ void un_init_kernel(const float* __restrict__ un, float* __restrict__ out_un) {
    size_t i = ((size_t)blockIdx.x * 256 + threadIdx.x) * 4;
    float4 v = *(const float4*)(&un[i]);
    v.x *= 0.9f; v.y *= 0.9f; v.z *= 0.9f; v.w *= 0.9f;
    *(float4*)(&out_un[i]) = v;
}

__global__ void un_scatter_kernel(const float* __restrict__ x, const int* __restrict__ idxbuf,
                                  float* __restrict__ out_un) {
    int n = blockIdx.x;
    int k = idxbuf[n];
    for (int d = threadIdx.x; d < D_; d += 256) {
        atomicAdd(&out_un[(size_t)d * K_ + k], 0.1f * x[(size_t)n * D_ + d]);
    }
}

// ---- new_cs + perplexity partials ----
__global__ void cs_kernel(const unsigned* __restrict__ counts, const float* __restrict__ cs,
                          float* __restrict__ out_cs,
                          double* __restrict__ ncs_part, double* __restrict__ ent_part) {
    int tid = threadIdx.x;
    int k = blockIdx.x * 256 + tid;
    float cnt = (float)counts[k];
    float ncs = 0.1f * cnt + 0.9f * cs[k];
    out_cs[k] = ncs;
    double p = (double)counts[k] / 8192.0;
    double ent = -p * log(p + 1e-20);

    __shared__ double s1[256], s2[256];
    s1[tid] = (double)ncs;
    s2[tid] = ent;
    __syncthreads();
    for (int s = 128; s > 0; s >>= 1) {
        if (tid < s) { s1[tid] += s1[tid + s]; s2[tid] += s2[tid + s]; }
        __syncthreads();
    }
    if (tid == 0) { ncs_part[blockIdx.x] = s1[0]; ent_part[blockIdx.x] = s2[0]; }
}

// ---- loss, perplexity, nsum ----
__global__ void scalars_kernel(const double* __restrict__ loss_part,
                               const double* __restrict__ ncs_part,
                               const double* __restrict__ ent_part,
                               float* __restrict__ out_loss, float* __restrict__ out_ppl,
                               double* __restrict__ nsum_out) {
    __shared__ double sr[256];
    double s = 0.0;
    for (int i = threadIdx.x; i < N_; i += 256) s += loss_part[i];
    sr[threadIdx.x] = s;
    __syncthreads();
    for (int t = 128; t > 0; t >>= 1) {
        if (threadIdx.x < t) sr[threadIdx.x] += sr[threadIdx.x + t];
        __syncthreads();
    }
    if (threadIdx.x == 0) {
        out_loss[0] = (float)(0.25 * (sr[0] / (double)((size_t)N_ * D_)));
        double nsum = 0.0, ent = 0.0;
        for (int i = 0; i < 32; ++i) { nsum += ncs_part[i]; ent += ent_part[i]; }
        out_ppl[0] = (float)exp(ent);
        nsum_out[0] = nsum;
    }
}

// ---- new_e = new_un / stable_cs ----
__global__ void newe_kernel(const float* __restrict__ out_un, const float* __restrict__ out_cs,
                            const double* __restrict__ nsum, float* __restrict__ out_e) {
    size_t i = ((size_t)blockIdx.x * 256 + threadIdx.x) * 4;
    int k = (int)(i & (K_ - 1));
    double n = nsum[0];
    double denom = n + 8192.0 * 1e-20;
    float4 u = *(const float4*)(&out_un[i]);
    float4 c = *(const float4*)(&out_cs[k]);
    float4 r;
    r.x = u.x / (float)(((double)c.x + 1e-20) / denom * n);
    r.y = u.y / (float)(((double)c.y + 1e-20) / denom * n);
    r.z = u.z / (float)(((double)c.z + 1e-20) / denom * n);
    r.w = u.w / (float)(((double)c.w + 1e-20) / denom * n);
    *(float4*)(&out_e[i]) = r;
}

extern "C" void kernel_launch(void* const* d_in, const int* in_sizes, int n_in,
                              void* d_out, int out_size, void* d_ws, size_t ws_size,
                              hipStream_t stream) {
    const float* x  = (const float*)d_in[0];
    const float* e  = (const float*)d_in[1];
    const float* cs = (const float*)d_in[2];
    const float* un = (const float*)d_in[3];

    float* out = (float*)d_out;
    float* out_q    = out;                    // 4194304
    float* out_loss = out + 4194304;          // 1
    float* out_ppl  = out + 4194305;          // 1
    float* out_idx  = out + 4194306;          // 8192
    float* out_e    = out + 4202498;          // 4194304
    float* out_cs   = out + 8396802;          // 8192
    float* out_un   = out + 8404994;          // 4194304

    // scratch aliases: out_q holds xh|xl, out_e holds ehT|elT until the epilogue
    unsigned short* xh  = (unsigned short*)out_q;
    unsigned short* xl  = xh + 4194304;
    unsigned short* ehT = (unsigned short*)out_e;
    unsigned short* elT = ehT + 4194304;

    char* ws = (char*)d_ws;
    unsigned* counts  = (unsigned*)ws;                 // 32768 B  [zeroed]
    unsigned* nflag   = (unsigned*)(ws + 32768);       // 256 B    [zeroed]
    float* x2f        = (float*)(ws + 36864);          // 32768 B
    float* e2f        = (float*)(ws + 69632);          // 32768 B
    float* pv         = (float*)(ws + 102400);         // 262144 B
    int*   pi         = (int*)(ws + 364544);           // 262144 B
    float* psec       = (float*)(ws + 626688);         // 262144 B
    int*   idxbuf     = (int*)(ws + 888832);           // 32768 B
    int*   flaglist   = (int*)(ws + 921600);           // 32768 B
    double* loss_part = (double*)(ws + 954368);        // 65536 B
    double* ncs_part  = (double*)(ws + 1019904);       // 256 B
    double* ent_part  = (double*)(ws + 1020160);       // 256 B
    double* nsum      = (double*)(ws + 1020416);       // 8 B

    hipMemsetAsync(d_ws, 0, 36864, stream);
    xsplit_kernel<<<4096, 256, 0, stream>>>(x, xh, xl);
    esplitT_kernel<<<dim3(K_ / 64, D_ / 64), 256, 0, stream>>>(e, ehT, elT);
    x2_kernel<<<N_ / 256, 256, 0, stream>>>(x, x2f);
    e2f_kernel<<<K_ / 256, 256, 0, stream>>>(e, e2f);
    argmin_mfma<<<dim3(KSLICES, N_ / 128), 256, 0, stream>>>(xh, xl, ehT, elT, x2f, e2f, pv, pi, psec);
    argmin_reduce<<<N_ / 256, 256, 0, stream>>>(pv, pi, psec, idxbuf, out_idx, flaglist, nflag);
    refine_kernel<<<1024, 256, 0, stream>>>(x, e, x2f, e2f, flaglist, nflag, idxbuf, out_idx);
    counts_kernel<<<N_ / 256, 256, 0, stream>>>(idxbuf, counts);
    quant_loss_kernel<<<N_, 256, 0, stream>>>(x, e, idxbuf, out_q, loss_part);
    un_init_kernel<<<4096, 256, 0, stream>>>(un, out_un);
    un_scatter_kernel<<<N_, 256, 0, stream>>>(x, idxbuf, out_un);
    cs_kernel<<<K_ / 256, 256, 0, stream>>>(counts, cs, out_cs, ncs_part, ent_part);
    scalars_kernel<<<1, 256, 0, stream>>>(loss_part, ncs_part, ent_part, out_loss, out_ppl, nsum);
    newe_kernel<<<4096, 256, 0, stream>>>(out_un, out_cs, nsum, out_e);
}

// Round 6
// 653.863 us; speedup vs baseline: 2.8483x; 1.4111x over previous
//
#include <hip/hip_runtime.h>
#include <math.h>

#define D_ 512
#define K_ 8192
#define N_ 8192
#define KSLICES 8
#define TAU 2.5e-3f

typedef __attribute__((ext_vector_type(8))) short bf16x8;
typedef __attribute__((ext_vector_type(8))) unsigned short u16x8;
typedef __attribute__((ext_vector_type(4))) float f32x4;

__device__ __forceinline__ unsigned short bf16_rne(float f) {
    unsigned u = __float_as_uint(f);
    unsigned r = (u + 0x7fffu + ((u >> 16) & 1u)) >> 16;
    return (unsigned short)r;
}
__device__ __forceinline__ float bf16_to_f(unsigned short h) {
    return __uint_as_float(((unsigned)h) << 16);
}

// ---- x2[n] = np.sum(x*x, axis=1) replicated: numpy pairwise f32 ----
__global__ void x2_kernel(const float* __restrict__ x, float* __restrict__ x2f) {
    int n = blockIdx.x * 256 + threadIdx.x;
    const float* row = &x[(size_t)n * D_];
    float b[4];
    #pragma unroll
    for (int blk = 0; blk < 4; ++blk) {
        const float* a = row + blk * 128;
        float r[8];
        #pragma unroll
        for (int j = 0; j < 8; ++j) { float v = a[j]; r[j] = __fmul_rn(v, v); }
        for (int i = 8; i < 128; i += 8) {
            #pragma unroll
            for (int j = 0; j < 8; ++j) {
                float v = a[i + j];
                r[j] = __fadd_rn(r[j], __fmul_rn(v, v));
            }
        }
        b[blk] = __fadd_rn(__fadd_rn(__fadd_rn(r[0], r[1]), __fadd_rn(r[2], r[3])),
                           __fadd_rn(__fadd_rn(r[4], r[5]), __fadd_rn(r[6], r[7])));
    }
    x2f[n] = __fadd_rn(__fadd_rn(b[0], b[1]), __fadd_rn(b[2], b[3]));
}

// ---- e2[k] = np.sum(e*e, axis=0) replicated: sequential f32 over d ----
__global__ void e2f_kernel(const float* __restrict__ e, float* __restrict__ e2f) {
    int k = blockIdx.x * 256 + threadIdx.x;
    float s = 0.0f;
    for (int d = 0; d < D_; ++d) {
        float v = e[(size_t)d * K_ + k];
        s = __fadd_rn(s, __fmul_rn(v, v));
    }
    e2f[k] = s;
}

// ---- split x into bf16 hi/lo, same [N][D] layout ----
__global__ void xsplit_kernel(const float* __restrict__ x,
                              unsigned short* __restrict__ xh, unsigned short* __restrict__ xl) {
    size_t i = ((size_t)blockIdx.x * 256 + threadIdx.x) * 4;
    float4 v = *(const float4*)&x[i];
    ushort4 h, l;
    h.x = bf16_rne(v.x); l.x = bf16_rne(__fsub_rn(v.x, bf16_to_f(h.x)));
    h.y = bf16_rne(v.y); l.y = bf16_rne(__fsub_rn(v.y, bf16_to_f(h.y)));
    h.z = bf16_rne(v.z); l.z = bf16_rne(__fsub_rn(v.z, bf16_to_f(h.z)));
    h.w = bf16_rne(v.w); l.w = bf16_rne(__fsub_rn(v.w, bf16_to_f(h.w)));
    *(ushort4*)&xh[i] = h;
    *(ushort4*)&xl[i] = l;
}

// ---- split e into bf16 hi/lo TRANSPOSED: ehT/elT are [K][D] ----
__global__ void esplitT_kernel(const float* __restrict__ e,
                               unsigned short* __restrict__ ehT, unsigned short* __restrict__ elT) {
    __shared__ float t[64][65];
    const int tid = threadIdx.x;
    const int k0 = blockIdx.x * 64;
    const int d0 = blockIdx.y * 64;
    #pragma unroll
    for (int it = 0; it < 4; ++it) {
        int dt = (tid >> 4) + it * 16;
        int c4 = (tid & 15) * 4;
        float4 v = *(const float4*)&e[(size_t)(d0 + dt) * K_ + k0 + c4];
        t[dt][c4 + 0] = v.x; t[dt][c4 + 1] = v.y; t[dt][c4 + 2] = v.z; t[dt][c4 + 3] = v.w;
    }
    __syncthreads();
    const int m = tid >> 2, ch = tid & 3;
    u16x8 h0, h1, l0, l1;
    #pragma unroll
    for (int j = 0; j < 8; ++j) {
        float f = t[ch * 16 + j][m];
        unsigned short hh = bf16_rne(f);
        h0[j] = hh; l0[j] = bf16_rne(__fsub_rn(f, bf16_to_f(hh)));
    }
    #pragma unroll
    for (int j = 0; j < 8; ++j) {
        float f = t[ch * 16 + 8 + j][m];
        unsigned short hh = bf16_rne(f);
        h1[j] = hh; l1[j] = bf16_rne(__fsub_rn(f, bf16_to_f(hh)));
    }
    size_t o = (size_t)(k0 + m) * D_ + d0 + ch * 16;
    *(u16x8*)&ehT[o] = h0; *(u16x8*)&ehT[o + 8] = h1;
    *(u16x8*)&elT[o] = l0; *(u16x8*)&elT[o + 8] = l1;
}

// ---- MFMA bf16-split distance pass: per-row (best, idx, second) per K-slice ----
__launch_bounds__(256, 2)
__global__ void argmin_mfma(const unsigned short* __restrict__ xh, const unsigned short* __restrict__ xl,
                            const unsigned short* __restrict__ ehT, const unsigned short* __restrict__ elT,
                            const float* __restrict__ x2f, const float* __restrict__ e2f,
                            float* __restrict__ pv, int* __restrict__ pi, float* __restrict__ psec) {
    __shared__ unsigned short smem[2][4][4096];
    __shared__ float e2s[128];

    const int tid = threadIdx.x;
    const int lane = tid & 63;
    const int wid = tid >> 6;
    const int wm = wid & 1, wn = wid >> 1;
    const int lidx = lane & 15, g = lane >> 4;
    const int rowbase = blockIdx.y * 128;
    const int kslice = blockIdx.x;

    float x2r[4];
    #pragma unroll
    for (int nt = 0; nt < 4; ++nt)
        x2r[nt] = x2f[rowbase + (wn << 6) + (nt << 4) + lidx];

    float best[4], sec[4]; int bi[4];
    #pragma unroll
    for (int nt = 0; nt < 4; ++nt) { best[nt] = 3.0e38f; sec[nt] = 3.0e38f; bi[nt] = 0; }

    const int f0 = tid,        r0 = f0 >> 2, s0 = f0 & 3, c0 = (s0 - (r0 >> 1)) & 3;
    const int f1 = tid + 256,  r1 = f1 >> 2, s1 = f1 & 3, c1 = (s1 - (r1 >> 1)) & 3;
    const size_t xo0 = (size_t)(rowbase + r0) * D_ + c0 * 8;
    const size_t xo1 = (size_t)(rowbase + r1) * D_ + c1 * 8;

    for (int cc = 0; cc < 8; ++cc) {
        const int codebase = kslice * 1024 + cc * 128;
        __syncthreads();
        if (tid < 128) e2s[tid] = e2f[codebase + tid];
        const size_t eo0 = (size_t)(codebase + r0) * D_ + c0 * 8;
        const size_t eo1 = (size_t)(codebase + r1) * D_ + c1 * 8;

        f32x4 acc_hi[4][4], acc_md[4][4];
        const f32x4 z4 = {0.0f, 0.0f, 0.0f, 0.0f};
        #pragma unroll
        for (int mt = 0; mt < 4; ++mt)
            #pragma unroll
            for (int nt = 0; nt < 4; ++nt) { acc_hi[mt][nt] = z4; acc_md[mt][nt] = z4; }

        u16x8 st[8];
        st[0] = *(const u16x8*)&xh[xo0]; st[1] = *(const u16x8*)&xl[xo0];
        st[2] = *(const u16x8*)&ehT[eo0]; st[3] = *(const u16x8*)&elT[eo0];
        st[4] = *(const u16x8*)&xh[xo1]; st[5] = *(const u16x8*)&xl[xo1];
        st[6] = *(const u16x8*)&ehT[eo1]; st[7] = *(const u16x8*)&elT[eo1];
        *(u16x8*)&smem[0][0][f0 * 8] = st[0]; *(u16x8*)&smem[0][1][f0 * 8] = st[1];
        *(u16x8*)&smem[0][2][f0 * 8] = st[2]; *(u16x8*)&smem[0][3][f0 * 8] = st[3];
        *(u16x8*)&smem[0][0][f1 * 8] = st[4]; *(u16x8*)&smem[0][1][f1 * 8] = st[5];
        *(u16x8*)&smem[0][2][f1 * 8] = st[6]; *(u16x8*)&smem[0][3][f1 * 8] = st[7];
        __syncthreads();

        for (int step = 0; step < 16; ++step) {
            const int cur = step & 1;
            if (step < 15) {
                const int d0 = (step + 1) << 5;
                st[0] = *(const u16x8*)&xh[xo0 + d0]; st[1] = *(const u16x8*)&xl[xo0 + d0];
                st[2] = *(const u16x8*)&ehT[eo0 + d0]; st[3] = *(const u16x8*)&elT[eo0 + d0];
                st[4] = *(const u16x8*)&xh[xo1 + d0]; st[5] = *(const u16x8*)&xl[xo1 + d0];
                st[6] = *(const u16x8*)&ehT[eo1 + d0]; st[7] = *(const u16x8*)&elT[eo1 + d0];
            }
            const unsigned short* XH = smem[cur][0];
            const unsigned short* XL = smem[cur][1];
            const unsigned short* EH = smem[cur][2];
            const unsigned short* EL = smem[cur][3];
            bf16x8 bh[4], bl[4];
            #pragma unroll
            for (int nt = 0; nt < 4; ++nt) {
                int n = (wn << 6) + (nt << 4) + lidx;
                int sb = (g + (n >> 1)) & 3;
                bh[nt] = *(const bf16x8*)&XH[n * 32 + sb * 8];
                bl[nt] = *(const bf16x8*)&XL[n * 32 + sb * 8];
            }
            #pragma unroll
            for (int mt = 0; mt < 4; ++mt) {
                int m = (wm << 6) + (mt << 4) + lidx;
                int sa = (g + (m >> 1)) & 3;
                bf16x8 ah = *(const bf16x8*)&EH[m * 32 + sa * 8];
                bf16x8 al = *(const bf16x8*)&EL[m * 32 + sa * 8];
                #pragma unroll
                for (int nt = 0; nt < 4; ++nt) {
                    acc_hi[mt][nt] = __builtin_amdgcn_mfma_f32_16x16x32_bf16(ah, bh[nt], acc_hi[mt][nt], 0, 0, 0);
                    acc_md[mt][nt] = __builtin_amdgcn_mfma_f32_16x16x32_bf16(ah, bl[nt], acc_md[mt][nt], 0, 0, 0);
                    acc_md[mt][nt] = __builtin_amdgcn_mfma_f32_16x16x32_bf16(al, bh[nt], acc_md[mt][nt], 0, 0, 0);
                }
            }
            if (step < 15) {
                unsigned short* DXH = smem[cur ^ 1][0];
                unsigned short* DXL = smem[cur ^ 1][1];
                unsigned short* DEH = smem[cur ^ 1][2];
                unsigned short* DEL = smem[cur ^ 1][3];
                *(u16x8*)&DXH[f0 * 8] = st[0]; *(u16x8*)&DXL[f0 * 8] = st[1];
                *(u16x8*)&DEH[f0 * 8] = st[2]; *(u16x8*)&DEL[f0 * 8] = st[3];
                *(u16x8*)&DXH[f1 * 8] = st[4]; *(u16x8*)&DXL[f1 * 8] = st[5];
                *(u16x8*)&DEH[f1 * 8] = st[6]; *(u16x8*)&DEL[f1 * 8] = st[7];
            }
            __syncthreads();
        }

        #pragma unroll
        for (int mt = 0; mt < 4; ++mt) {
            #pragma unroll
            for (int r = 0; r < 4; ++r) {
                const int ml = (wm << 6) + (mt << 4) + (g << 2) + r;
                const float e2k = e2s[ml];
                const int kg = codebase + ml;
                #pragma unroll
                for (int nt = 0; nt < 4; ++nt) {
                    float dot = __fadd_rn(acc_hi[mt][nt][r], acc_md[mt][nt][r]);
                    float s = __fsub_rn(__fadd_rn(x2r[nt], e2k), __fmul_rn(2.0f, dot));
                    if (s < best[nt]) { sec[nt] = best[nt]; best[nt] = s; bi[nt] = kg; }
                    else if (s < sec[nt]) sec[nt] = s;
                }
            }
        }
    }

    __syncthreads();
    float* redB = (float*)&smem[0][0][0];
    float* redS = redB + 256;
    int*   redI = (int*)(redS + 256);
    #pragma unroll
    for (int nt = 0; nt < 4; ++nt) {
        #pragma unroll
        for (int off = 16; off < 64; off <<= 1) {
            float ov = __shfl_xor(best[nt], off);
            float os = __shfl_xor(sec[nt], off);
            int   oi = __shfl_xor(bi[nt], off);
            if (ov < best[nt] || (ov == best[nt] && oi < bi[nt])) {
                sec[nt] = fminf(best[nt], os);
                best[nt] = ov; bi[nt] = oi;
            } else {
                sec[nt] = fminf(sec[nt], ov);
            }
        }
        if (g == 0) {
            int rl = (wn << 6) + (nt << 4) + lidx;
            redB[rl * 2 + wm] = best[nt];
            redS[rl * 2 + wm] = sec[nt];
            redI[rl * 2 + wm] = bi[nt];
        }
    }
    __syncthreads();
    if (tid < 128) {
        float b0 = redB[tid * 2], b1 = redB[tid * 2 + 1];
        float q0 = redS[tid * 2], q1 = redS[tid * 2 + 1];
        int i0 = redI[tid * 2], i1 = redI[tid * 2 + 1];
        float bv, sv; int bx;
        if (b1 < b0 || (b1 == b0 && i1 < i0)) { bv = b1; bx = i1; sv = fminf(q1, b0); }
        else { bv = b0; bx = i0; sv = fminf(q0, b1); }
        int grow = rowbase + tid;
        pv[(size_t)grow * KSLICES + kslice] = bv;
        pi[(size_t)grow * KSLICES + kslice] = bx;
        psec[(size_t)grow * KSLICES + kslice] = sv;
    }
}

// ---- reduce split-K partials -> enc_idx; flag ambiguous rows ----
__global__ void argmin_reduce(const float* __restrict__ pv, const int* __restrict__ pi,
                              const float* __restrict__ psec,
                              int* __restrict__ idxbuf, float* __restrict__ out_idx,
                              int* __restrict__ flaglist, unsigned* __restrict__ nflag) {
    int n = blockIdx.x * 256 + threadIdx.x;
    float bv = 3.0e38f, sv = 3.0e38f; int bi = 0x7fffffff;
    #pragma unroll
    for (int s = 0; s < KSLICES; ++s) {
        float vv = pv[(size_t)n * KSLICES + s];
        int   ii = pi[(size_t)n * KSLICES + s];
        float ss = psec[(size_t)n * KSLICES + s];
        if (vv < bv || (vv == bv && ii < bi)) {
            sv = fminf(fminf(sv, ss), bv);
            bv = vv; bi = ii;
        } else {
            sv = fminf(sv, vv);
        }
    }
    idxbuf[n] = bi;
    out_idx[n] = (float)bi;
    if (sv - bv < TAU) {
        unsigned pos = atomicAdd(nflag, 1u);
        flaglist[pos] = n;
    }
}

// ---- exact refine, parallel: work item = (flagged row, 256-code chunk) ----
// np-replicated f32 scoring on f64-exact dot; per-row winner via packed u64 atomicMin
__global__ void refine_kernel(const float* __restrict__ x, const float* __restrict__ e,
                              const float* __restrict__ x2f, const float* __restrict__ e2f,
                              const int* __restrict__ flaglist, const unsigned* __restrict__ nflag,
                              unsigned long long* __restrict__ packed) {
    __shared__ float xrow[D_];
    const int tid = threadIdx.x;
    const unsigned total = *nflag * 32u;
    for (unsigned w = blockIdx.x; w < total; w += gridDim.x) {
        const int n = flaglist[w >> 5];
        const int k = (int)((w & 31u) << 8) + tid;
        __syncthreads();
        for (int d = tid; d < D_; d += 256) xrow[d] = x[(size_t)n * D_ + d];
        __syncthreads();
        double a0 = 0.0, a1 = 0.0, a2 = 0.0, a3 = 0.0;
        const float* ek = &e[k];
        #pragma unroll 2
        for (int d = 0; d < D_; d += 4) {
            a0 = fma((double)xrow[d + 0], (double)ek[(size_t)(d + 0) * K_], a0);
            a1 = fma((double)xrow[d + 1], (double)ek[(size_t)(d + 1) * K_], a1);
            a2 = fma((double)xrow[d + 2], (double)ek[(size_t)(d + 2) * K_], a2);
            a3 = fma((double)xrow[d + 3], (double)ek[(size_t)(d + 3) * K_], a3);
        }
        double dot = (a0 + a1) + (a2 + a3);
        float md = (float)dot;
        float s = __fsub_rn(__fadd_rn(x2f[n], e2f[k]), __fmul_rn(2.0f, md));
        unsigned b = __float_as_uint(s);
        unsigned key = b ^ ((b >> 31) ? 0xFFFFFFFFu : 0x80000000u);  // monotone map
        unsigned long long pk = (((unsigned long long)key) << 32) | (unsigned)k;
        atomicMin(&packed[n], pk);
    }
}

__global__ void refine_finalize(const int* __restrict__ flaglist, const unsigned* __restrict__ nflag,
                                const unsigned long long* __restrict__ packed,
                                int* __restrict__ idxbuf, float* __restrict__ out_idx) {
    unsigned i = blockIdx.x * 256 + threadIdx.x;
    if (i < *nflag) {
        int n = flaglist[i];
        int k = (int)(packed[n] & 0xFFFFFFFFull);
        idxbuf[n] = k;
        out_idx[n] = (float)k;
    }
}

// ---- histogram after refine ----
__global__ void counts_kernel(const int* __restrict__ idxbuf, unsigned* __restrict__ counts) {
    int n = blockIdx.x * 256 + threadIdx.x;
    atomicAdd(&counts[idxbuf[n]], 1u);
}

// ---- gather quantized + straight-through + loss partials ----
__global__ void quant_loss_kernel(const float* __restrict__ x, const float* __restrict__ e,
                                  const int* __restrict__ idxbuf,
                                  float* __restrict__ qout, double* __restrict__ loss_part) {
    int n = blockIdx.x;
    int k = idxbuf[n];
    double part = 0.0;
    for (int d = threadIdx.x; d < D_; d += 256) {
        float q = e[(size_t)d * K_ + k];
        float xv = x[(size_t)n * D_ + d];
        float df = q - xv;
        qout[(size_t)n * D_ + d] = xv + df;
        part = fma((double)df, (double)df, part);
    }
    __shared__ double sr[256];
    sr[threadIdx.x] = part;
    __syncthreads();
    for (int s = 128; s > 0; s >>= 1) {
        if (threadIdx.x < s) sr[threadIdx.x] += sr[threadIdx.x + s];
        __syncthreads();
    }
    if (threadIdx.x == 0) loss_part[n] = sr[0];
}

// ---- new_un = 0.9*un, then scatter 0.1*x ----
__global__ void un_init_kernel(const float* __restrict__ un, float* __restrict__ out_un) {
    size_t i = ((size_t)blockIdx.x * 256 + threadIdx.x) * 4;
    float4 v = *(const float4*)(&un[i]);
    v.x *= 0.9f; v.y *= 0.9f; v.z *= 0.9f; v.w *= 0.9f;
    *(float4*)(&out_un[i]) = v;
}

__global__ void un_scatter_kernel(const float* __restrict__ x, const int* __restrict__ idxbuf,
                                  float* __restrict__ out_un) {
    int n = blockIdx.x;
    int k = idxbuf[n];
    for (int d = threadIdx.x; d < D_; d += 256) {
        atomicAdd(&out_un[(size_t)d * K_ + k], 0.1f * x[(size_t)n * D_ + d]);
    }
}

// ---- new_cs + perplexity partials ----
__global__ void cs_kernel(const unsigned* __restrict__ counts, const float* __restrict__ cs,
                          float* __restrict__ out_cs,
                          double* __restrict__ ncs_part, double* __restrict__ ent_part) {
    int tid = threadIdx.x;
    int k = blockIdx.x * 256 + tid;
    float cnt = (float)counts[k];
    float ncs = 0.1f * cnt + 0.9f * cs[k];
    out_cs[k] = ncs;
    double p = (double)counts[k] / 8192.0;
    double ent = -p * log(p + 1e-20);

    __shared__ double s1[256], s2[256];
    s1[tid] = (double)ncs;
    s2[tid] = ent;
    __syncthreads();
    for (int s = 128; s > 0; s >>= 1) {
        if (tid < s) { s1[tid] += s1[tid + s]; s2[tid] += s2[tid + s]; }
        __syncthreads();
    }
    if (tid == 0) { ncs_part[blockIdx.x] = s1[0]; ent_part[blockIdx.x] = s2[0]; }
}

// ---- loss, perplexity, nsum ----
__global__ void scalars_kernel(const double* __restrict__ loss_part,
                               const double* __restrict__ ncs_part,
                               const double* __restrict__ ent_part,
                               float* __restrict__ out_loss, float* __restrict__ out_ppl,
                               double* __restrict__ nsum_out) {
    __shared__ double sr[256];
    double s = 0.0;
    for (int i = threadIdx.x; i < N_; i += 256) s += loss_part[i];
    sr[threadIdx.x] = s;
    __syncthreads();
    for (int t = 128; t > 0; t >>= 1) {
        if (threadIdx.x < t) sr[threadIdx.x] += sr[threadIdx.x + t];
        __syncthreads();
    }
    if (threadIdx.x == 0) {
        out_loss[0] = (float)(0.25 * (sr[0] / (double)((size_t)N_ * D_)));
        double nsum = 0.0, ent = 0.0;
        for (int i = 0; i < 32; ++i) { nsum += ncs_part[i]; ent += ent_part[i]; }
        out_ppl[0] = (float)exp(ent);
        nsum_out[0] = nsum;
    }
}

// ---- new_e = new_un / stable_cs ----
__global__ void newe_kernel(const float* __restrict__ out_un, const float* __restrict__ out_cs,
                            const double* __restrict__ nsum, float* __restrict__ out_e) {
    size_t i = ((size_t)blockIdx.x * 256 + threadIdx.x) * 4;
    int k = (int)(i & (K_ - 1));
    double n = nsum[0];
    double denom = n + 8192.0 * 1e-20;
    float4 u = *(const float4*)(&out_un[i]);
    float4 c = *(const float4*)(&out_cs[k]);
    float4 r;
    r.x = u.x / (float)(((double)c.x + 1e-20) / denom * n);
    r.y = u.y / (float)(((double)c.y + 1e-20) / denom * n);
    r.z = u.z / (float)(((double)c.z + 1e-20) / denom * n);
    r.w = u.w / (float)(((double)c.w + 1e-20) / denom * n);
    *(float4*)(&out_e[i]) = r;
}

extern "C" void kernel_launch(void* const* d_in, const int* in_sizes, int n_in,
                              void* d_out, int out_size, void* d_ws, size_t ws_size,
                              hipStream_t stream) {
    const float* x  = (const float*)d_in[0];
    const float* e  = (const float*)d_in[1];
    const float* cs = (const float*)d_in[2];
    const float* un = (const float*)d_in[3];

    float* out = (float*)d_out;
    float* out_q    = out;                    // 4194304
    float* out_loss = out + 4194304;          // 1
    float* out_ppl  = out + 4194305;          // 1
    float* out_idx  = out + 4194306;          // 8192
    float* out_e    = out + 4202498;          // 4194304
    float* out_cs   = out + 8396802;          // 8192
    float* out_un   = out + 8404994;          // 4194304

    // scratch aliases: out_q holds xh|xl, out_e holds ehT|elT until the epilogue
    unsigned short* xh  = (unsigned short*)out_q;
    unsigned short* xl  = xh + 4194304;
    unsigned short* ehT = (unsigned short*)out_e;
    unsigned short* elT = ehT + 4194304;

    char* ws = (char*)d_ws;
    unsigned* counts  = (unsigned*)ws;                 // 32768 B  [zeroed]
    unsigned* nflag   = (unsigned*)(ws + 32768);       // 256 B    [zeroed]
    float* x2f        = (float*)(ws + 36864);          // 32768 B
    float* e2f        = (float*)(ws + 69632);          // 32768 B
    float* pv         = (float*)(ws + 102400);         // 262144 B
    int*   pi         = (int*)(ws + 364544);           // 262144 B
    float* psec       = (float*)(ws + 626688);         // 262144 B
    int*   idxbuf     = (int*)(ws + 888832);           // 32768 B
    int*   flaglist   = (int*)(ws + 921600);           // 32768 B
    double* loss_part = (double*)(ws + 954368);        // 65536 B
    double* ncs_part  = (double*)(ws + 1019904);       // 256 B
    double* ent_part  = (double*)(ws + 1020160);       // 256 B
    double* nsum      = (double*)(ws + 1020416);       // 8 B
    // packed per-row refine results alias psec (dead after argmin_reduce)
    unsigned long long* packed = (unsigned long long*)(ws + 626688);  // 65536 B

    hipMemsetAsync(d_ws, 0, 36864, stream);
    xsplit_kernel<<<4096, 256, 0, stream>>>(x, xh, xl);
    esplitT_kernel<<<dim3(K_ / 64, D_ / 64), 256, 0, stream>>>(e, ehT, elT);
    x2_kernel<<<N_ / 256, 256, 0, stream>>>(x, x2f);
    e2f_kernel<<<K_ / 256, 256, 0, stream>>>(e, e2f);
    argmin_mfma<<<dim3(KSLICES, N_ / 128), 256, 0, stream>>>(xh, xl, ehT, elT, x2f, e2f, pv, pi, psec);
    argmin_reduce<<<N_ / 256, 256, 0, stream>>>(pv, pi, psec, idxbuf, out_idx, flaglist, nflag);
    hipMemsetAsync(packed, 0xFF, 65536, stream);   // after psec is consumed
    refine_kernel<<<2048, 256, 0, stream>>>(x, e, x2f, e2f, flaglist, nflag, packed);
    refine_finalize<<<32, 256, 0, stream>>>(flaglist, nflag, packed, idxbuf, out_idx);
    counts_kernel<<<N_ / 256, 256, 0, stream>>>(idxbuf, counts);
    quant_loss_kernel<<<N_, 256, 0, stream>>>(x, e, idxbuf, out_q, loss_part);
    un_init_kernel<<<4096, 256, 0, stream>>>(un, out_un);
    un_scatter_kernel<<<N_, 256, 0, stream>>>(x, idxbuf, out_un);
    cs_kernel<<<K_ / 256, 256, 0, stream>>>(counts, cs, out_cs, ncs_part, ent_part);
    scalars_kernel<<<1, 256, 0, stream>>>(loss_part, ncs_part, ent_part, out_loss, out_ppl, nsum);
    newe_kernel<<<4096, 256, 0, stream>>>(out_un, out_cs, nsum, out_e);
}

// Round 7
// 492.380 us; speedup vs baseline: 3.7825x; 1.3280x over previous
//
#include <hip/hip_runtime.h>
#include <math.h>

#define D_ 512
#define K_ 8192
#define N_ 8192
#define KSLICES 8
#define TAU 0.01f

typedef _Float16 f16x8 __attribute__((ext_vector_type(8)));
typedef __attribute__((ext_vector_type(4))) float f32x4;

// ---- x2[n] = np.sum(x*x, axis=1) replicated: numpy pairwise f32 ----
__global__ void x2_kernel(const float* __restrict__ x, float* __restrict__ x2f) {
    int n = blockIdx.x * 256 + threadIdx.x;
    const float* row = &x[(size_t)n * D_];
    float b[4];
    #pragma unroll
    for (int blk = 0; blk < 4; ++blk) {
        const float* a = row + blk * 128;
        float r[8];
        #pragma unroll
        for (int j = 0; j < 8; ++j) { float v = a[j]; r[j] = __fmul_rn(v, v); }
        for (int i = 8; i < 128; i += 8) {
            #pragma unroll
            for (int j = 0; j < 8; ++j) {
                float v = a[i + j];
                r[j] = __fadd_rn(r[j], __fmul_rn(v, v));
            }
        }
        b[blk] = __fadd_rn(__fadd_rn(__fadd_rn(r[0], r[1]), __fadd_rn(r[2], r[3])),
                           __fadd_rn(__fadd_rn(r[4], r[5]), __fadd_rn(r[6], r[7])));
    }
    x2f[n] = __fadd_rn(__fadd_rn(b[0], b[1]), __fadd_rn(b[2], b[3]));
}

// ---- e2[k] = np.sum(e*e, axis=0) replicated: sequential f32 over d ----
__global__ void e2f_kernel(const float* __restrict__ e, float* __restrict__ e2f) {
    int k = blockIdx.x * 256 + threadIdx.x;
    float s = 0.0f;
    for (int d = 0; d < D_; ++d) {
        float v = e[(size_t)d * K_ + k];
        s = __fadd_rn(s, __fmul_rn(v, v));
    }
    e2f[k] = s;
}

// ---- x -> fp16, same [N][D] layout ----
__global__ void xcvt_kernel(const float* __restrict__ x, _Float16* __restrict__ xf) {
    size_t i = ((size_t)blockIdx.x * 256 + threadIdx.x) * 8;
    float4 a = *(const float4*)&x[i];
    float4 b = *(const float4*)&x[i + 4];
    f16x8 h;
    h[0] = (_Float16)a.x; h[1] = (_Float16)a.y; h[2] = (_Float16)a.z; h[3] = (_Float16)a.w;
    h[4] = (_Float16)b.x; h[5] = (_Float16)b.y; h[6] = (_Float16)b.z; h[7] = (_Float16)b.w;
    *(f16x8*)&xf[i] = h;
}

// ---- e -> fp16 TRANSPOSED: efT is [K][D] ----
__global__ void ecvtT_kernel(const float* __restrict__ e, _Float16* __restrict__ efT) {
    __shared__ float t[64][65];
    const int tid = threadIdx.x;
    const int k0 = blockIdx.x * 64;
    const int d0 = blockIdx.y * 64;
    #pragma unroll
    for (int it = 0; it < 4; ++it) {
        int dt = (tid >> 4) + it * 16;
        int c4 = (tid & 15) * 4;
        float4 v = *(const float4*)&e[(size_t)(d0 + dt) * K_ + k0 + c4];
        t[dt][c4 + 0] = v.x; t[dt][c4 + 1] = v.y; t[dt][c4 + 2] = v.z; t[dt][c4 + 3] = v.w;
    }
    __syncthreads();
    const int m = tid >> 2, ch = tid & 3;
    f16x8 h0, h1;
    #pragma unroll
    for (int j = 0; j < 8; ++j) h0[j] = (_Float16)t[ch * 16 + j][m];
    #pragma unroll
    for (int j = 0; j < 8; ++j) h1[j] = (_Float16)t[ch * 16 + 8 + j][m];
    size_t o = (size_t)(k0 + m) * D_ + d0 + ch * 16;
    *(f16x8*)&efT[o] = h0;
    *(f16x8*)&efT[o + 8] = h1;
}

// ---- fp16 MFMA distance pass: per (row, kslice) top-4 candidates ----
// Block: 128 rows x 1024-code slice in 4 chunks of 256. Waves 2x2 (wm codes, wn rows).
__launch_bounds__(256, 2)
__global__ void argmin_mfma(const _Float16* __restrict__ xf, const _Float16* __restrict__ efT,
                            const float* __restrict__ x2f, const float* __restrict__ e2f,
                            float* __restrict__ pv4, int* __restrict__ pi4) {
    __shared__ _Float16 XS[2][4096];   // [128 rows][32 d]
    __shared__ _Float16 ES[2][8192];   // [256 codes][32 d]
    __shared__ float e2s[256];

    const int tid = threadIdx.x;
    const int lane = tid & 63;
    const int wid = tid >> 6;
    const int wm = wid & 1, wn = wid >> 1;
    const int lidx = lane & 15, g = lane >> 4;
    const int rowbase = blockIdx.y * 128;
    const int kslice = blockIdx.x;

    float x2r[4];
    #pragma unroll
    for (int nt = 0; nt < 4; ++nt)
        x2r[nt] = x2f[rowbase + (wn << 6) + (nt << 4) + lidx];

    float best[4], sec[4]; int bi[4], si[4];
    #pragma unroll
    for (int nt = 0; nt < 4; ++nt) {
        best[nt] = 3.0e38f; sec[nt] = 3.0e38f; bi[nt] = 0x7ffffffe; si[nt] = 0x7fffffff;
    }

    // staging maps (slot rotation, proven R5/R6): chunk f -> row=f>>2, slot=f&3,
    // src 16B-chunk c = (slot - (row>>1)) & 3
    const int fx0 = tid,       rx0 = fx0 >> 2, cx0 = ((fx0 & 3) - (rx0 >> 1)) & 3;
    const int fx1 = tid + 256, rx1 = fx1 >> 2, cx1 = ((fx1 & 3) - (rx1 >> 1)) & 3;
    const size_t xo0 = (size_t)(rowbase + rx0) * D_ + cx0 * 8;
    const size_t xo1 = (size_t)(rowbase + rx1) * D_ + cx1 * 8;
    int fe[4], re[4], ce[4];
    #pragma unroll
    for (int j = 0; j < 4; ++j) {
        fe[j] = tid + j * 256; re[j] = fe[j] >> 2; ce[j] = ((fe[j] & 3) - (re[j] >> 1)) & 3;
    }

    for (int cc = 0; cc < 4; ++cc) {
        const int codebase = kslice * 1024 + cc * 256;
        __syncthreads();
        e2s[tid] = e2f[codebase + tid];

        f32x4 acc[8][4];
        const f32x4 z4 = {0.0f, 0.0f, 0.0f, 0.0f};
        #pragma unroll
        for (int mt = 0; mt < 8; ++mt)
            #pragma unroll
            for (int nt = 0; nt < 4; ++nt) acc[mt][nt] = z4;

        f16x8 st[6];
        // stage step 0 -> buf 0
        st[0] = *(const f16x8*)&xf[xo0];
        st[1] = *(const f16x8*)&xf[xo1];
        #pragma unroll
        for (int j = 0; j < 4; ++j)
            st[2 + j] = *(const f16x8*)&efT[(size_t)(codebase + re[j]) * D_ + ce[j] * 8];
        *(f16x8*)&XS[0][fx0 * 8] = st[0];
        *(f16x8*)&XS[0][fx1 * 8] = st[1];
        #pragma unroll
        for (int j = 0; j < 4; ++j) *(f16x8*)&ES[0][fe[j] * 8] = st[2 + j];
        __syncthreads();

        for (int step = 0; step < 16; ++step) {
            const int cur = step & 1;
            if (step < 15) {   // prefetch next d-step while MFMAs run
                const int d0 = (step + 1) << 5;
                st[0] = *(const f16x8*)&xf[xo0 + d0];
                st[1] = *(const f16x8*)&xf[xo1 + d0];
                #pragma unroll
                for (int j = 0; j < 4; ++j)
                    st[2 + j] = *(const f16x8*)&efT[(size_t)(codebase + re[j]) * D_ + d0 + ce[j] * 8];
            }
            f16x8 bh[4];
            #pragma unroll
            for (int nt = 0; nt < 4; ++nt) {
                int n = (wn << 6) + (nt << 4) + lidx;
                int sb = (g + (n >> 1)) & 3;
                bh[nt] = *(const f16x8*)&XS[cur][n * 32 + sb * 8];
            }
            #pragma unroll
            for (int mt = 0; mt < 8; ++mt) {
                int m = (wm << 7) + (mt << 4) + lidx;
                int sa = (g + (m >> 1)) & 3;
                f16x8 ah = *(const f16x8*)&ES[cur][m * 32 + sa * 8];
                #pragma unroll
                for (int nt = 0; nt < 4; ++nt)
                    acc[mt][nt] = __builtin_amdgcn_mfma_f32_16x16x32_f16(ah, bh[nt], acc[mt][nt], 0, 0, 0);
            }
            if (step < 15) {
                *(f16x8*)&XS[cur ^ 1][fx0 * 8] = st[0];
                *(f16x8*)&XS[cur ^ 1][fx1 * 8] = st[1];
                #pragma unroll
                for (int j = 0; j < 4; ++j) *(f16x8*)&ES[cur ^ 1][fe[j] * 8] = st[2 + j];
            }
            __syncthreads();
        }

        // score: code ml = wm*128 + mt*16 + g*4 + r; x-row col = wn*64 + nt*16 + lidx
        #pragma unroll
        for (int mt = 0; mt < 8; ++mt) {
            #pragma unroll
            for (int r = 0; r < 4; ++r) {
                const int ml = (wm << 7) + (mt << 4) + (g << 2) + r;
                const float e2k = e2s[ml];
                const int kg = codebase + ml;
                #pragma unroll
                for (int nt = 0; nt < 4; ++nt) {
                    float dot = acc[mt][nt][r];
                    float s = __fsub_rn(__fadd_rn(x2r[nt], e2k), __fmul_rn(2.0f, dot));
                    if (s < best[nt]) {
                        sec[nt] = best[nt]; si[nt] = bi[nt];
                        best[nt] = s; bi[nt] = kg;
                    } else if (s < sec[nt]) {
                        sec[nt] = s; si[nt] = kg;
                    }
                }
            }
        }
    }

    // ---- per (row, slice) top-4 from 8 threads x best2 = 16 entries ----
    __syncthreads();
    float* entV = (float*)XS;   // 2048 floats = 128 rows x 16
    int*   entI = (int*)ES;     // 2048 ints
    #pragma unroll
    for (int nt = 0; nt < 4; ++nt) {
        int rl = (wn << 6) + (nt << 4) + lidx;
        int slot = ((wm << 2) + g) << 1;
        entV[rl * 16 + slot] = best[nt];  entI[rl * 16 + slot] = bi[nt];
        entV[rl * 16 + slot + 1] = sec[nt]; entI[rl * 16 + slot + 1] = si[nt];
    }
    __syncthreads();
    if (tid < 128) {
        float v4[4] = {3.0e38f, 3.0e38f, 3.0e38f, 3.0e38f};
        int i4[4] = {0x7fffffff, 0x7fffffff, 0x7fffffff, 0x7fffffff};
        #pragma unroll
        for (int t2 = 0; t2 < 16; ++t2) {
            float v = entV[tid * 16 + t2]; int i = entI[tid * 16 + t2];
            #pragma unroll
            for (int p = 0; p < 4; ++p) {
                bool better = (v < v4[p]) || (v == v4[p] && i < i4[p]);
                if (better) {
                    float tv = v4[p]; v4[p] = v; v = tv;
                    int ti = i4[p]; i4[p] = i; i = ti;
                }
            }
        }
        size_t o = (size_t)(rowbase + tid) * 32 + kslice * 4;
        #pragma unroll
        for (int p = 0; p < 4; ++p) { pv4[o + p] = v4[p]; pi4[o + p] = i4[p]; }
    }
}

// ---- reduce top-4 lists -> enc_idx; flag ambiguous rows ----
__global__ void argmin_reduce(const float* __restrict__ pv4, const int* __restrict__ pi4,
                              int* __restrict__ idxbuf, float* __restrict__ out_idx,
                              int* __restrict__ flaglist, unsigned* __restrict__ nflag) {
    int n = blockIdx.x * 256 + threadIdx.x;
    float bv = 3.0e38f, sv = 3.0e38f; int bi = 0x7fffffff;
    for (int j = 0; j < 32; ++j) {
        float v = pv4[(size_t)n * 32 + j]; int i = pi4[(size_t)n * 32 + j];
        if (v < bv || (v == bv && i < bi)) { sv = bv; bv = v; bi = i; }
        else if (v < sv) sv = v;
    }
    idxbuf[n] = bi;
    out_idx[n] = (float)bi;
    if (sv - bv < TAU) {
        unsigned pos = atomicAdd(nflag, 1u);
        flaglist[pos] = n;
    }
}

// ---- exact refine of flagged rows over their 32 candidates only ----
__launch_bounds__(256, 2)
__global__ void refine_kernel(const float* __restrict__ x, const float* __restrict__ e,
                              const float* __restrict__ x2f, const float* __restrict__ e2f,
                              const int* __restrict__ flaglist, const unsigned* __restrict__ nflag,
                              const float* __restrict__ pv4, const int* __restrict__ pi4,
                              int* __restrict__ idxbuf, float* __restrict__ out_idx) {
    __shared__ float xrow[D_];
    __shared__ double part[32][8];
    __shared__ int candi[32];
    __shared__ float sv[32];
    const int tid = threadIdx.x;
    const unsigned nf = *nflag;
    for (unsigned f = blockIdx.x; f < nf; f += gridDim.x) {
        const int n = flaglist[f];
        __syncthreads();
        if (tid < 32) candi[tid] = pi4[(size_t)n * 32 + tid];
        for (int d = tid; d < D_; d += 256) xrow[d] = x[(size_t)n * D_ + d];
        __syncthreads();
        const int c = tid >> 3, j = tid & 7;
        const int k = candi[c];
        double a = 0.0;
        #pragma unroll 8
        for (int d = j; d < D_; d += 8)
            a = fma((double)xrow[d], (double)e[(size_t)d * K_ + k], a);
        part[c][j] = a;
        __syncthreads();
        if (j == 0) {
            double dot = ((part[c][0] + part[c][1]) + (part[c][2] + part[c][3]))
                       + ((part[c][4] + part[c][5]) + (part[c][6] + part[c][7]));
            float md = (float)dot;
            sv[c] = __fsub_rn(__fadd_rn(x2f[n], e2f[k]), __fmul_rn(2.0f, md));
        }
        __syncthreads();
        if (tid == 0) {
            float bv = 3.0e38f; int bi = 0x7fffffff;
            for (int c2 = 0; c2 < 32; ++c2) {
                float v = sv[c2]; int i2 = candi[c2];
                if (v < bv || (v == bv && i2 < bi)) { bv = v; bi = i2; }
            }
            idxbuf[n] = bi; out_idx[n] = (float)bi;
        }
        __syncthreads();
    }
}

// ---- histogram after refine ----
__global__ void counts_kernel(const int* __restrict__ idxbuf, unsigned* __restrict__ counts) {
    int n = blockIdx.x * 256 + threadIdx.x;
    atomicAdd(&counts[idxbuf[n]], 1u);
}

// ---- gather quantized + straight-through + loss partials ----
__global__ void quant_loss_kernel(const float* __restrict__ x, const float* __restrict__ e,
                                  const int* __restrict__ idxbuf,
                                  float* __restrict__ qout, double* __restrict__ loss_part) {
    int n = blockIdx.x;
    int k = idxbuf[n];
    double part = 0.0;
    for (int d = threadIdx.x; d < D_; d += 256) {
        float q = e[(size_t)d * K_ + k];
        float xv = x[(size_t)n * D_ + d];
        float df = q - xv;
        qout[(size_t)n * D_ + d] = xv + df;
        part = fma((double)df, (double)df, part);
    }
    __shared__ double sr[256];
    sr[threadIdx.x] = part;
    __syncthreads();
    for (int s = 128; s > 0; s >>= 1) {
        if (threadIdx.x < s) sr[threadIdx.x] += sr[threadIdx.x + s];
        __syncthreads();
    }
    if (threadIdx.x == 0) loss_part[n] = sr[0];
}

// ---- new_un = 0.9*un, then scatter 0.1*x ----
__global__ void un_init_kernel(const float* __restrict__ un, float* __restrict__ out_un) {
    size_t i = ((size_t)blockIdx.x * 256 + threadIdx.x) * 4;
    float4 v = *(const float4*)(&un[i]);
    v.x *= 0.9f; v.y *= 0.9f; v.z *= 0.9f; v.w *= 0.9f;
    *(float4*)(&out_un[i]) = v;
}

__global__ void un_scatter_kernel(const float* __restrict__ x, const int* __restrict__ idxbuf,
                                  float* __restrict__ out_un) {
    int n = blockIdx.x;
    int k = idxbuf[n];
    for (int d = threadIdx.x; d < D_; d += 256) {
        atomicAdd(&out_un[(size_t)d * K_ + k], 0.1f * x[(size_t)n * D_ + d]);
    }
}

// ---- new_cs + perplexity partials ----
__global__ void cs_kernel(const unsigned* __restrict__ counts, const float* __restrict__ cs,
                          float* __restrict__ out_cs,
                          double* __restrict__ ncs_part, double* __restrict__ ent_part) {
    int tid = threadIdx.x;
    int k = blockIdx.x * 256 + tid;
    float cnt = (float)counts[k];
    float ncs = 0.1f * cnt + 0.9f * cs[k];
    out_cs[k] = ncs;
    double p = (double)counts[k] / 8192.0;
    double ent = -p * log(p + 1e-20);

    __shared__ double s1[256], s2[256];
    s1[tid] = (double)ncs;
    s2[tid] = ent;
    __syncthreads();
    for (int s = 128; s > 0; s >>= 1) {
        if (tid < s) { s1[tid] += s1[tid + s]; s2[tid] += s2[tid + s]; }
        __syncthreads();
    }
    if (tid == 0) { ncs_part[blockIdx.x] = s1[0]; ent_part[blockIdx.x] = s2[0]; }
}

// ---- loss, perplexity, nsum ----
__global__ void scalars_kernel(const double* __restrict__ loss_part,
                               const double* __restrict__ ncs_part,
                               const double* __restrict__ ent_part,
                               float* __restrict__ out_loss, float* __restrict__ out_ppl,
                               double* __restrict__ nsum_out) {
    __shared__ double sr[256];
    double s = 0.0;
    for (int i = threadIdx.x; i < N_; i += 256) s += loss_part[i];
    sr[threadIdx.x] = s;
    __syncthreads();
    for (int t = 128; t > 0; t >>= 1) {
        if (threadIdx.x < t) sr[threadIdx.x] += sr[threadIdx.x + t];
        __syncthreads();
    }
    if (threadIdx.x == 0) {
        out_loss[0] = (float)(0.25 * (sr[0] / (double)((size_t)N_ * D_)));
        double nsum = 0.0, ent = 0.0;
        for (int i = 0; i < 32; ++i) { nsum += ncs_part[i]; ent += ent_part[i]; }
        out_ppl[0] = (float)exp(ent);
        nsum_out[0] = nsum;
    }
}

// ---- new_e = new_un / stable_cs ----
__global__ void newe_kernel(const float* __restrict__ out_un, const float* __restrict__ out_cs,
                            const double* __restrict__ nsum, float* __restrict__ out_e) {
    size_t i = ((size_t)blockIdx.x * 256 + threadIdx.x) * 4;
    int k = (int)(i & (K_ - 1));
    double n = nsum[0];
    double denom = n + 8192.0 * 1e-20;
    float4 u = *(const float4*)(&out_un[i]);
    float4 c = *(const float4*)(&out_cs[k]);
    float4 r;
    r.x = u.x / (float)(((double)c.x + 1e-20) / denom * n);
    r.y = u.y / (float)(((double)c.y + 1e-20) / denom * n);
    r.z = u.z / (float)(((double)c.z + 1e-20) / denom * n);
    r.w = u.w / (float)(((double)c.w + 1e-20) / denom * n);
    *(float4*)(&out_e[i]) = r;
}

extern "C" void kernel_launch(void* const* d_in, const int* in_sizes, int n_in,
                              void* d_out, int out_size, void* d_ws, size_t ws_size,
                              hipStream_t stream) {
    const float* x  = (const float*)d_in[0];
    const float* e  = (const float*)d_in[1];
    const float* cs = (const float*)d_in[2];
    const float* un = (const float*)d_in[3];

    float* out = (float*)d_out;
    float* out_q    = out;                    // 4194304
    float* out_loss = out + 4194304;          // 1
    float* out_ppl  = out + 4194305;          // 1
    float* out_idx  = out + 4194306;          // 8192
    float* out_e    = out + 4202498;          // 4194304
    float* out_cs   = out + 8396802;          // 8192
    float* out_un   = out + 8404994;          // 4194304

    // scratch aliases (all consumed before their hosting output is written):
    _Float16* xf16 = (_Float16*)out_q;            // 8 MB in out_q (written by quant_loss later)
    _Float16* efT  = (_Float16*)out_e;            // 8 MB in out_e (written by newe last)
    float* pv4 = (float*)out_un;                  // 1 MB  in out_un (written by un_init later)
    int*   pi4 = (int*)(out_un + 262144);         // 1 MB

    char* ws = (char*)d_ws;
    unsigned* counts  = (unsigned*)ws;                 // 32768 B  [zeroed]
    unsigned* nflag   = (unsigned*)(ws + 32768);       // 4096 B   [zeroed]
    float* x2f        = (float*)(ws + 36864);          // 32768 B
    float* e2f        = (float*)(ws + 69632);          // 32768 B
    int*   idxbuf     = (int*)(ws + 102400);           // 32768 B
    int*   flaglist   = (int*)(ws + 135168);           // 32768 B
    double* loss_part = (double*)(ws + 167936);        // 65536 B
    double* ncs_part  = (double*)(ws + 233472);        // 256 B
    double* ent_part  = (double*)(ws + 233728);        // 256 B
    double* nsum      = (double*)(ws + 233984);        // 8 B

    hipMemsetAsync(d_ws, 0, 36864, stream);
    xcvt_kernel<<<2048, 256, 0, stream>>>(x, xf16);
    ecvtT_kernel<<<dim3(K_ / 64, D_ / 64), 256, 0, stream>>>(e, efT);
    x2_kernel<<<N_ / 256, 256, 0, stream>>>(x, x2f);
    e2f_kernel<<<K_ / 256, 256, 0, stream>>>(e, e2f);
    argmin_mfma<<<dim3(KSLICES, N_ / 128), 256, 0, stream>>>(xf16, efT, x2f, e2f, pv4, pi4);
    argmin_reduce<<<N_ / 256, 256, 0, stream>>>(pv4, pi4, idxbuf, out_idx, flaglist, nflag);
    refine_kernel<<<256, 256, 0, stream>>>(x, e, x2f, e2f, flaglist, nflag, pv4, pi4, idxbuf, out_idx);
    counts_kernel<<<N_ / 256, 256, 0, stream>>>(idxbuf, counts);
    quant_loss_kernel<<<N_, 256, 0, stream>>>(x, e, idxbuf, out_q, loss_part);
    un_init_kernel<<<4096, 256, 0, stream>>>(un, out_un);
    un_scatter_kernel<<<N_, 256, 0, stream>>>(x, idxbuf, out_un);
    cs_kernel<<<K_ / 256, 256, 0, stream>>>(counts, cs, out_cs, ncs_part, ent_part);
    scalars_kernel<<<1, 256, 0, stream>>>(loss_part, ncs_part, ent_part, out_loss, out_ppl, nsum);
    newe_kernel<<<4096, 256, 0, stream>>>(out_un, out_cs, nsum, out_e);
}